// Round 1
// baseline (14751.328 us; speedup 1.0000x reference)
//
#include <hip/hip_runtime.h>

// ---------------------------------------------------------------------------
// Problem constants (from reference)
// ---------------------------------------------------------------------------
constexpr int NN = 50000;            // nodes
constexpr int NE = 800000;           // edges (before self loops)
constexpr int NP = 262144;           // pairs
constexpr int ET = NE + NN;          // edges incl self loops = 850000

#define M_INIT 0x007FFFFFu          // ordered-uint encoding of -inf

__device__ __forceinline__ unsigned enc_f(float f) {
  unsigned u = __float_as_uint(f);
  return (u & 0x80000000u) ? ~u : (u | 0x80000000u);
}
__device__ __forceinline__ float dec_f(unsigned uo) {
  unsigned u = (uo & 0x80000000u) ? (uo ^ 0x80000000u) : ~uo;
  return __uint_as_float(u);
}

// ---------------------------------------------------------------------------
// Generic tiled fp32 GEMM: C[M,N] = A[M,K] @ B[K,N] (+bias)
// If idx0 != nullptr: A-row r is gather-concat: k<256 -> A[idx0[r]*256+k],
// else A[idx1[r]*256+(k-256)]  (pair feature build fused into the GEMM).
// ---------------------------------------------------------------------------
#define BM 64
#define BN 64
#define BK 16

__global__ __launch_bounds__(256)
void gemm_f32(const float* __restrict__ A, const float* __restrict__ B,
              float* __restrict__ C, int M, int N, int K,
              const float* __restrict__ bias,
              const int* __restrict__ idx0, const int* __restrict__ idx1)
{
  __shared__ float As[BK][BM + 1];
  __shared__ float Bs[BK][BN];
  const int tid = threadIdx.x;
  const int tx = tid & 15, ty = tid >> 4;
  const int row0 = blockIdx.y * BM, col0 = blockIdx.x * BN;
  float acc[4][4] = {};

  for (int kt = 0; kt < K; kt += BK) {
    // A tile: 64 rows x 16 k
    #pragma unroll
    for (int i = tid; i < BM * BK; i += 256) {
      int m = i >> 4, k = i & 15;
      int r = row0 + m, kk = kt + k;
      float v = 0.f;
      if (r < M && kk < K) {
        if (idx0) {
          int node = (kk < 256) ? idx0[r] : idx1[r];
          v = A[(size_t)node * 256 + (kk & 255)];
        } else {
          v = A[(size_t)r * K + kk];
        }
      }
      As[k][m] = v;
    }
    // B tile: 16 k x 64 n
    #pragma unroll
    for (int i = tid; i < BK * BN; i += 256) {
      int k = i >> 6, n = i & 63;
      int kk = kt + k, c = col0 + n;
      Bs[k][n] = (kk < K && c < N) ? B[(size_t)kk * N + c] : 0.f;
    }
    __syncthreads();
    #pragma unroll
    for (int k = 0; k < BK; ++k) {
      float a[4], b[4];
      #pragma unroll
      for (int i = 0; i < 4; ++i) a[i] = As[k][ty * 4 + i];
      #pragma unroll
      for (int j = 0; j < 4; ++j) b[j] = Bs[k][tx * 4 + j];
      #pragma unroll
      for (int i = 0; i < 4; ++i)
        #pragma unroll
        for (int j = 0; j < 4; ++j)
          acc[i][j] = fmaf(a[i], b[j], acc[i][j]);
    }
    __syncthreads();
  }

  #pragma unroll
  for (int i = 0; i < 4; ++i) {
    int r = row0 + ty * 4 + i;
    if (r >= M) continue;
    #pragma unroll
    for (int j = 0; j < 4; ++j) {
      int c = col0 + tx * 4 + j;
      if (c >= N) continue;
      float v = acc[i][j];
      if (bias) v += bias[c];
      C[(size_t)r * N + c] = v;
    }
  }
}

// ---------------------------------------------------------------------------
// GAT helper kernels
// ---------------------------------------------------------------------------

// per-(node,head) attention coefficients: one wave per (node,head)
__global__ void node_coeffs(const float* __restrict__ h,
                            const float* __restrict__ a_src,
                            const float* __restrict__ a_dst,
                            float* __restrict__ s_n, float* __restrict__ d_n)
{
  int wid = (blockIdx.x * blockDim.x + threadIdx.x) >> 6;
  int lane = threadIdx.x & 63;
  if (wid >= NN * 2) return;
  int node = wid >> 1, head = wid & 1;
  const float4* hp = (const float4*)(h + (size_t)node * 512 + head * 256);
  const float4* ap = (const float4*)(a_src + head * 256);
  const float4* dp = (const float4*)(a_dst + head * 256);
  float4 hv = hp[lane], av = ap[lane], dv = dp[lane];
  float ss = hv.x * av.x + hv.y * av.y + hv.z * av.z + hv.w * av.w;
  float dd = hv.x * dv.x + hv.y * dv.y + hv.z * dv.z + hv.w * dv.w;
  #pragma unroll
  for (int off = 32; off > 0; off >>= 1) {
    ss += __shfl_down(ss, off);
    dd += __shfl_down(dd, off);
  }
  if (lane == 0) { s_n[wid] = ss; d_n[wid] = dd; }
}

__global__ void fill_u32(unsigned* __restrict__ p, unsigned v, int n)
{
  int i = blockIdx.x * blockDim.x + threadIdx.x;
  if (i < n) p[i] = v;
}

// alpha = leaky_relu(s[src]+d[dst]); segment max over dst (ordered-uint atomics)
__global__ void edge_alpha(const int* __restrict__ ei,
                           const float* __restrict__ s_n, const float* __restrict__ d_n,
                           float* __restrict__ alpha, unsigned* __restrict__ m_u)
{
  int e = blockIdx.x * blockDim.x + threadIdx.x;
  if (e >= ET) return;
  int src, dst;
  if (e < NE) { src = ei[e]; dst = ei[NE + e]; }
  else        { src = dst = e - NE; }
  #pragma unroll
  for (int h = 0; h < 2; ++h) {
    float a = s_n[src * 2 + h] + d_n[dst * 2 + h];
    a = a > 0.f ? a : 0.2f * a;
    alpha[(size_t)e * 2 + h] = a;
    atomicMax(&m_u[dst * 2 + h], enc_f(a));
  }
}

// e = exp(alpha - m[dst]); segment sum over dst
__global__ void edge_expsum(const int* __restrict__ ei,
                            float* __restrict__ alpha,
                            const unsigned* __restrict__ m_u,
                            float* __restrict__ zsum)
{
  int e = blockIdx.x * blockDim.x + threadIdx.x;
  if (e >= ET) return;
  int dst = (e < NE) ? ei[NE + e] : e - NE;
  #pragma unroll
  for (int h = 0; h < 2; ++h) {
    unsigned mu = m_u[dst * 2 + h];
    float m = (mu == M_INIT) ? 0.f : dec_f(mu);
    float ev = expf(alpha[(size_t)e * 2 + h] - m);
    alpha[(size_t)e * 2 + h] = ev;
    unsafeAtomicAdd(&zsum[dst * 2 + h], ev);
  }
}

// msg scatter: one wave per (edge,head); acc[dst] += h[src] * w
__global__ void edge_message(const int* __restrict__ ei,
                             const float* __restrict__ h,
                             const float* __restrict__ ev,
                             const float* __restrict__ zsum,
                             float* __restrict__ acc)
{
  int gid = blockIdx.x * blockDim.x + threadIdx.x;
  int wid = gid >> 6;
  int lane = threadIdx.x & 63;
  if (wid >= ET * 2) return;
  int e = wid >> 1, head = wid & 1;
  int src, dst;
  if (e < NE) { src = ei[e]; dst = ei[NE + e]; }
  else        { src = dst = e - NE; }
  float w = ev[(size_t)e * 2 + head] / (zsum[dst * 2 + head] + 1e-16f);
  const float4* hp = (const float4*)(h + (size_t)src * 512 + head * 256);
  float4 v = hp[lane];
  float* ap = acc + (size_t)dst * 512 + head * 256 + lane * 4;
  unsafeAtomicAdd(ap + 0, v.x * w);
  unsafeAtomicAdd(ap + 1, v.y * w);
  unsafeAtomicAdd(ap + 2, v.z * w);
  unsafeAtomicAdd(ap + 3, v.w * w);
}

// t[n,c] = mean over heads + bias
__global__ void head_mean_bias(const float* __restrict__ acc,
                               const float* __restrict__ bias,
                               float* __restrict__ t)
{
  int i = blockIdx.x * blockDim.x + threadIdx.x;
  if (i >= NN * 256) return;
  int n = i >> 8, c = i & 255;
  t[i] = 0.5f * (acc[(size_t)n * 512 + c] + acc[(size_t)n * 512 + 256 + c]) + bias[c];
}

// ---------------------------------------------------------------------------
// BatchNorm: column stats (double accumulation) + apply(+ReLU)
// ---------------------------------------------------------------------------
__global__ void col_stats(const float* __restrict__ x, double* __restrict__ stats,
                          int rows, int cols)
{
  int c = threadIdx.x;           // blockDim.x == cols
  double s = 0.0, q = 0.0;
  for (int r = blockIdx.x; r < rows; r += gridDim.x) {
    float v = x[(size_t)r * cols + c];
    s += v;
    q += (double)v * (double)v;
  }
  unsafeAtomicAdd(&stats[c], s);
  unsafeAtomicAdd(&stats[cols + c], q);
}

__global__ void bn_apply_relu(const float* __restrict__ x, float* __restrict__ y,
                              const double* __restrict__ stats,
                              const float* __restrict__ g, const float* __restrict__ b,
                              int rows, int cols, int relu)
{
  int i = blockIdx.x * blockDim.x + threadIdx.x;
  if (i >= rows * cols) return;
  int c = i % cols;
  float mean = (float)(stats[c] / rows);
  float var = (float)(stats[cols + c] / rows) - mean * mean;
  float rs = rsqrtf(var + 1e-5f);
  float v = g[c] * (x[i] - mean) * rs + b[c];
  if (relu) v = fmaxf(v, 0.f);
  y[i] = v;
}

// ---------------------------------------------------------------------------
// Host-side GAT layer sequence
// ---------------------------------------------------------------------------
static void gat_layer(const float* xin, int Kin,
                      const float* W, const float* asrc, const float* adst,
                      const float* bias, const float* bng, const float* bnb,
                      const int* ei,
                      float* h, float* acc, float* feat_out,
                      float* alpha, unsigned* m_u, float* zsum,
                      float* s_n, float* d_n, double* stats,
                      hipStream_t st)
{
  dim3 b256(256);
  // h = xin @ W  [NN, 512]
  gemm_f32<<<dim3(8, (NN + 63) / 64), b256, 0, st>>>(xin, W, h, NN, 512, Kin,
                                                     nullptr, nullptr, nullptr);
  node_coeffs<<<(NN * 2 * 64 + 255) / 256, b256, 0, st>>>(h, asrc, adst, s_n, d_n);
  fill_u32<<<(NN * 2 + 255) / 256, b256, 0, st>>>(m_u, M_INIT, NN * 2);
  hipMemsetAsync(zsum, 0, (size_t)NN * 2 * sizeof(float), st);
  hipMemsetAsync(acc, 0, (size_t)NN * 512 * sizeof(float), st);
  edge_alpha<<<(ET + 255) / 256, b256, 0, st>>>(ei, s_n, d_n, alpha, m_u);
  edge_expsum<<<(ET + 255) / 256, b256, 0, st>>>(ei, alpha, m_u, zsum);
  edge_message<<<(ET * 2 * 64 + 255) / 256, b256, 0, st>>>(ei, h, alpha, zsum, acc);
  head_mean_bias<<<(NN * 256 + 255) / 256, b256, 0, st>>>(acc, bias, h); // t -> h buf
  hipMemsetAsync(stats, 0, 2 * 256 * sizeof(double), st);
  col_stats<<<256, 256, 0, st>>>(h, stats, NN, 256);
  bn_apply_relu<<<(NN * 256 + 255) / 256, b256, 0, st>>>(h, feat_out, stats, bng, bnb,
                                                         NN, 256, 1);
}

// ---------------------------------------------------------------------------
// kernel_launch
// ---------------------------------------------------------------------------
extern "C" void kernel_launch(void* const* d_in, const int* in_sizes, int n_in,
                              void* d_out, int out_size, void* d_ws, size_t ws_size,
                              hipStream_t stream)
{
  const int*   edge_index = (const int*)d_in[0];
  const float* x      = (const float*)d_in[1];
  const int*   edge_id = (const int*)d_in[2];
  const float* W1     = (const float*)d_in[3];
  const float* a_src1 = (const float*)d_in[4];
  const float* a_dst1 = (const float*)d_in[5];
  const float* b1     = (const float*)d_in[6];
  const float* bn1_g  = (const float*)d_in[7];
  const float* bn1_b  = (const float*)d_in[8];
  const float* W2     = (const float*)d_in[9];
  const float* a_src2 = (const float*)d_in[10];
  const float* a_dst2 = (const float*)d_in[11];
  const float* b2     = (const float*)d_in[12];
  const float* bn2_g  = (const float*)d_in[13];
  const float* bn2_b  = (const float*)d_in[14];
  const float* lw1    = (const float*)d_in[15];
  const float* lb1    = (const float*)d_in[16];
  const float* bn3_g  = (const float*)d_in[17];
  const float* bn3_b  = (const float*)d_in[18];
  const float* lw2    = (const float*)d_in[19];
  const float* lb2    = (const float*)d_in[20];
  const float* bn4_g  = (const float*)d_in[21];
  const float* bn4_b  = (const float*)d_in[22];
  const float* fw     = (const float*)d_in[23];
  const float* fb     = (const float*)d_in[24];
  float* out = (float*)d_out;

  // ---- workspace arena (explicit aliasing; ~362 MB total) ----
  char* w = (char*)d_ws;
  float*    h_buf  = (float*)(w + 0);                    // [NN,512] 102.4 MB (also t [NN,256])
  float*    acc_b  = (float*)(w + 102400000);            // [NN,512] 102.4 MB
  float*    z1     = (float*)(w + 0);                    // [NP,128] 128 MB (aliases h/acc, dead by then)
  float*    z2     = (float*)(w + 134217728);            // [NP,128] 128 MB
  float*    feat1  = (float*)(w + 268435456);            // [NN,256] 51.2 MB
  float*    feat2  = (float*)(w + 319635456);            // [NN,256] 51.2 MB
  float*    alpha  = (float*)(w + 370835456);            // [ET,2]   6.8 MB
  unsigned* m_u    = (unsigned*)(w + 377635456);         // [NN,2]
  float*    zsum   = (float*)(w + 378035456);            // [NN,2]
  double*   stats  = (double*)(w + 378435456);           // 2*256 doubles
  float*    s_n    = (float*)(w + 378439552);            // [NN,2]
  float*    d_n    = (float*)(w + 378839552);            // [NN,2]

  dim3 b256(256);

  // ---- GAT layer 1: x[NN,572] -> feat1[NN,256] ----
  gat_layer(x, 572, W1, a_src1, a_dst1, b1, bn1_g, bn1_b, edge_index,
            h_buf, acc_b, feat1, alpha, m_u, zsum, s_n, d_n, stats, stream);

  // ---- GAT layer 2: feat1 -> feat2 ----
  gat_layer(feat1, 256, W2, a_src2, a_dst2, b2, bn2_g, bn2_b, edge_index,
            h_buf, acc_b, feat2, alpha, m_u, zsum, s_n, d_n, stats, stream);

  // ---- pair MLP ----
  // z1 = concat(feat2[i0], feat2[i1]) @ lw1 + lb1   [NP,128]
  gemm_f32<<<dim3(2, NP / 64), b256, 0, stream>>>(feat2, lw1, z1, NP, 128, 512,
                                                  lb1, edge_id, edge_id + NP);
  hipMemsetAsync(stats, 0, 2 * 128 * sizeof(double), stream);
  col_stats<<<512, 128, 0, stream>>>(z1, stats, NP, 128);
  bn_apply_relu<<<(NP * 128 + 255) / 256, b256, 0, stream>>>(z1, z1, stats, bn3_g, bn3_b,
                                                             NP, 128, 1);
  // z2 = z1 @ lw2 + lb2
  gemm_f32<<<dim3(2, NP / 64), b256, 0, stream>>>(z1, lw2, z2, NP, 128, 128,
                                                  lb2, nullptr, nullptr);
  hipMemsetAsync(stats, 0, 2 * 128 * sizeof(double), stream);
  col_stats<<<512, 128, 0, stream>>>(z2, stats, NP, 128);
  bn_apply_relu<<<(NP * 128 + 255) / 256, b256, 0, stream>>>(z2, z2, stats, bn4_g, bn4_b,
                                                             NP, 128, 1);
  // out = z2 @ fw + fb   [NP,65]
  gemm_f32<<<dim3(2, NP / 64), b256, 0, stream>>>(z2, fw, out, NP, 65, 128,
                                                  fb, nullptr, nullptr);
}

// Round 2
// 3755.740 us; speedup vs baseline: 3.9277x; 3.9277x over previous
//
#include <hip/hip_runtime.h>

// ---------------------------------------------------------------------------
// Problem constants (from reference)
// ---------------------------------------------------------------------------
constexpr int NN = 50000;            // nodes
constexpr int NE = 800000;           // edges (before self loops)
constexpr int NP = 262144;           // pairs
constexpr int ET = NE + NN;          // edges incl self loops = 850000

// ---------------------------------------------------------------------------
// Generic tiled fp32 GEMM: C[M,N] = A[M,K] @ B[K,N] (+bias)
// If idx0 != nullptr: A-row r is gather-concat: k<256 -> A[idx0[r]*256+k],
// else A[idx1[r]*256+(k-256)]  (pair feature build fused into the GEMM).
// ---------------------------------------------------------------------------
#define BM 64
#define BN 64
#define BK 16

__global__ __launch_bounds__(256)
void gemm_f32(const float* __restrict__ A, const float* __restrict__ B,
              float* __restrict__ C, int M, int N, int K,
              const float* __restrict__ bias,
              const int* __restrict__ idx0, const int* __restrict__ idx1)
{
  __shared__ float As[BK][BM + 1];
  __shared__ float Bs[BK][BN];
  const int tid = threadIdx.x;
  const int tx = tid & 15, ty = tid >> 4;
  const int row0 = blockIdx.y * BM, col0 = blockIdx.x * BN;
  float acc[4][4] = {};

  for (int kt = 0; kt < K; kt += BK) {
    #pragma unroll
    for (int i = tid; i < BM * BK; i += 256) {
      int m = i >> 4, k = i & 15;
      int r = row0 + m, kk = kt + k;
      float v = 0.f;
      if (r < M && kk < K) {
        if (idx0) {
          int node = (kk < 256) ? idx0[r] : idx1[r];
          v = A[(size_t)node * 256 + (kk & 255)];
        } else {
          v = A[(size_t)r * K + kk];
        }
      }
      As[k][m] = v;
    }
    #pragma unroll
    for (int i = tid; i < BK * BN; i += 256) {
      int k = i >> 6, n = i & 63;
      int kk = kt + k, c = col0 + n;
      Bs[k][n] = (kk < K && c < N) ? B[(size_t)kk * N + c] : 0.f;
    }
    __syncthreads();
    #pragma unroll
    for (int k = 0; k < BK; ++k) {
      float a[4], b[4];
      #pragma unroll
      for (int i = 0; i < 4; ++i) a[i] = As[k][ty * 4 + i];
      #pragma unroll
      for (int j = 0; j < 4; ++j) b[j] = Bs[k][tx * 4 + j];
      #pragma unroll
      for (int i = 0; i < 4; ++i)
        #pragma unroll
        for (int j = 0; j < 4; ++j)
          acc[i][j] = fmaf(a[i], b[j], acc[i][j]);
    }
    __syncthreads();
  }

  #pragma unroll
  for (int i = 0; i < 4; ++i) {
    int r = row0 + ty * 4 + i;
    if (r >= M) continue;
    #pragma unroll
    for (int j = 0; j < 4; ++j) {
      int c = col0 + tx * 4 + j;
      if (c >= N) continue;
      float v = acc[i][j];
      if (bias) v += bias[c];
      C[(size_t)r * N + c] = v;
    }
  }
}

// ---------------------------------------------------------------------------
// CSR build (graph identical for both layers -> build once per call)
// ---------------------------------------------------------------------------
__global__ void deg_count(const int* __restrict__ ei, int* __restrict__ deg)
{
  int e = blockIdx.x * blockDim.x + threadIdx.x;
  if (e >= ET) return;
  int dst = (e < NE) ? ei[NE + e] : e - NE;
  atomicAdd(&deg[dst], 1);
}

// single-block exclusive scan over NN elements -> rowptr[NN+1]
__global__ __launch_bounds__(1024)
void scan_deg(const int* __restrict__ deg, int* __restrict__ rowptr,
              int* __restrict__ cursor)
{
  __shared__ int tot[1024];
  const int t = threadIdx.x;
  const int CH = (NN + 1023) / 1024;           // 49
  const int base = t * CH;
  int s = 0;
  for (int i = 0; i < CH; ++i) {
    int idx = base + i;
    if (idx < NN) s += deg[idx];
  }
  tot[t] = s;
  __syncthreads();
  // Hillis-Steele inclusive scan
  for (int off = 1; off < 1024; off <<= 1) {
    int v = (t >= off) ? tot[t - off] : 0;
    __syncthreads();
    tot[t] += v;
    __syncthreads();
  }
  int run = (t == 0) ? 0 : tot[t - 1];
  for (int i = 0; i < CH; ++i) {
    int idx = base + i;
    if (idx <= NN) { rowptr[idx] = run; if (idx < NN) cursor[idx] = run; }
    if (idx < NN) run += deg[idx];
  }
}

__global__ void scatter_edges(const int* __restrict__ ei, int* __restrict__ cursor,
                              int* __restrict__ csr_src)
{
  int e = blockIdx.x * blockDim.x + threadIdx.x;
  if (e >= ET) return;
  int src, dst;
  if (e < NE) { src = ei[e]; dst = ei[NE + e]; }
  else        { src = dst = e - NE; }
  int pos = atomicAdd(&cursor[dst], 1);
  csr_src[pos] = src;
}

// ---------------------------------------------------------------------------
// GAT helper kernels
// ---------------------------------------------------------------------------

// per-(node,head) attention coefficients: one wave per (node,head)
__global__ void node_coeffs(const float* __restrict__ h,
                            const float* __restrict__ a_src,
                            const float* __restrict__ a_dst,
                            float* __restrict__ s_n, float* __restrict__ d_n)
{
  int wid = (blockIdx.x * blockDim.x + threadIdx.x) >> 6;
  int lane = threadIdx.x & 63;
  if (wid >= NN * 2) return;
  int node = wid >> 1, head = wid & 1;
  const float4* hp = (const float4*)(h + (size_t)node * 512 + head * 256);
  const float4* ap = (const float4*)(a_src + head * 256);
  const float4* dp = (const float4*)(a_dst + head * 256);
  float4 hv = hp[lane], av = ap[lane], dv = dp[lane];
  float ss = hv.x * av.x + hv.y * av.y + hv.z * av.z + hv.w * av.w;
  float dd = hv.x * dv.x + hv.y * dv.y + hv.z * dv.z + hv.w * dv.w;
  #pragma unroll
  for (int off = 32; off > 0; off >>= 1) {
    ss += __shfl_down(ss, off);
    dd += __shfl_down(dd, off);
  }
  if (lane == 0) { s_n[wid] = ss; d_n[wid] = dd; }
}

// One wave per dst node. Computes edge softmax (max, sum) from s_n/d_n and
// aggregates weighted h[src] rows; writes head-mean + bias. No atomics.
__global__ __launch_bounds__(256)
void gat_aggregate(const int* __restrict__ rowptr, const int* __restrict__ csr_src,
                   const float* __restrict__ h,
                   const float* __restrict__ s_n, const float* __restrict__ d_n,
                   const float* __restrict__ bias, float* __restrict__ outp)
{
  int wid = (blockIdx.x * blockDim.x + threadIdx.x) >> 6;
  int lane = threadIdx.x & 63;
  if (wid >= NN) return;
  const int dst = wid;
  const int beg = rowptr[dst], end = rowptr[dst + 1];
  const float d0 = d_n[dst * 2 + 0], d1 = d_n[dst * 2 + 1];
  const float2* sn2 = (const float2*)s_n;

  // pass 1: per-head max (lane-parallel over edges)
  float m0 = -1e30f, m1 = -1e30f;
  for (int i = beg + lane; i < end; i += 64) {
    float2 sv = sn2[csr_src[i]];
    float a0 = sv.x + d0; a0 = a0 > 0.f ? a0 : 0.2f * a0;
    float a1 = sv.y + d1; a1 = a1 > 0.f ? a1 : 0.2f * a1;
    m0 = fmaxf(m0, a0); m1 = fmaxf(m1, a1);
  }
  #pragma unroll
  for (int off = 32; off > 0; off >>= 1) {
    m0 = fmaxf(m0, __shfl_xor(m0, off));
    m1 = fmaxf(m1, __shfl_xor(m1, off));
  }
  // self loop guarantees end > beg, so m finite

  // pass 2: exp-sum (lane-parallel)
  float z0 = 0.f, z1 = 0.f;
  for (int i = beg + lane; i < end; i += 64) {
    float2 sv = sn2[csr_src[i]];
    float a0 = sv.x + d0; a0 = a0 > 0.f ? a0 : 0.2f * a0;
    float a1 = sv.y + d1; a1 = a1 > 0.f ? a1 : 0.2f * a1;
    z0 += __expf(a0 - m0);
    z1 += __expf(a1 - m1);
  }
  #pragma unroll
  for (int off = 32; off > 0; off >>= 1) {
    z0 += __shfl_xor(z0, off);
    z1 += __shfl_xor(z1, off);
  }
  const float rz0 = 1.f / (z0 + 1e-16f);
  const float rz1 = 1.f / (z1 + 1e-16f);

  // pass 3: sequential over edges; wave cooperatively loads h[src] (512 f32)
  float4 acc0 = {0.f, 0.f, 0.f, 0.f};
  float4 acc1 = {0.f, 0.f, 0.f, 0.f};
  for (int i = beg; i < end; ++i) {
    int s = csr_src[i];
    // wave-uniform weights (each lane computes the same values; s_n L2-hot)
    float2 sv = sn2[s];
    float a0 = sv.x + d0; a0 = a0 > 0.f ? a0 : 0.2f * a0;
    float a1 = sv.y + d1; a1 = a1 > 0.f ? a1 : 0.2f * a1;
    float w0 = __expf(a0 - m0) * rz0;
    float w1 = __expf(a1 - m1) * rz1;
    const float4* hp = (const float4*)(h + (size_t)s * 512);
    float4 v0 = hp[lane];        // head 0: channels lane*4..lane*4+3
    float4 v1 = hp[64 + lane];   // head 1
    acc0.x = fmaf(v0.x, w0, acc0.x); acc0.y = fmaf(v0.y, w0, acc0.y);
    acc0.z = fmaf(v0.z, w0, acc0.z); acc0.w = fmaf(v0.w, w0, acc0.w);
    acc1.x = fmaf(v1.x, w1, acc1.x); acc1.y = fmaf(v1.y, w1, acc1.y);
    acc1.z = fmaf(v1.z, w1, acc1.z); acc1.w = fmaf(v1.w, w1, acc1.w);
  }

  // head mean + bias, single coalesced write
  const float4 bb = ((const float4*)bias)[lane];
  float4 o;
  o.x = 0.5f * (acc0.x + acc1.x) + bb.x;
  o.y = 0.5f * (acc0.y + acc1.y) + bb.y;
  o.z = 0.5f * (acc0.z + acc1.z) + bb.z;
  o.w = 0.5f * (acc0.w + acc1.w) + bb.w;
  ((float4*)(outp + (size_t)dst * 256))[lane] = o;
}

// ---------------------------------------------------------------------------
// BatchNorm: column stats (double accumulation) + apply(+ReLU)
// ---------------------------------------------------------------------------
__global__ void col_stats(const float* __restrict__ x, double* __restrict__ stats,
                          int rows, int cols)
{
  int c = threadIdx.x;           // blockDim.x == cols
  double s = 0.0, q = 0.0;
  for (int r = blockIdx.x; r < rows; r += gridDim.x) {
    float v = x[(size_t)r * cols + c];
    s += v;
    q += (double)v * (double)v;
  }
  unsafeAtomicAdd(&stats[c], s);
  unsafeAtomicAdd(&stats[cols + c], q);
}

__global__ void bn_apply_relu(const float* __restrict__ x, float* __restrict__ y,
                              const double* __restrict__ stats,
                              const float* __restrict__ g, const float* __restrict__ b,
                              int rows, int cols, int relu)
{
  int i = blockIdx.x * blockDim.x + threadIdx.x;
  if (i >= rows * cols) return;
  int c = i % cols;
  float mean = (float)(stats[c] / rows);
  float var = (float)(stats[cols + c] / rows) - mean * mean;
  float rs = rsqrtf(var + 1e-5f);
  float v = g[c] * (x[i] - mean) * rs + b[c];
  if (relu) v = fmaxf(v, 0.f);
  y[i] = v;
}

// ---------------------------------------------------------------------------
// Host-side GAT layer sequence
// ---------------------------------------------------------------------------
static void gat_layer(const float* xin, int Kin,
                      const float* W, const float* asrc, const float* adst,
                      const float* bias, const float* bng, const float* bnb,
                      const int* rowptr, const int* csr_src,
                      float* h, float* t, float* feat_out,
                      float* s_n, float* d_n, double* stats,
                      hipStream_t st)
{
  dim3 b256(256);
  // h = xin @ W  [NN, 512]
  gemm_f32<<<dim3(8, (NN + 63) / 64), b256, 0, st>>>(xin, W, h, NN, 512, Kin,
                                                     nullptr, nullptr, nullptr);
  node_coeffs<<<(NN * 2 * 64 + 255) / 256, b256, 0, st>>>(h, asrc, adst, s_n, d_n);
  gat_aggregate<<<(NN * 64 + 255) / 256, b256, 0, st>>>(rowptr, csr_src, h,
                                                        s_n, d_n, bias, t);
  hipMemsetAsync(stats, 0, 2 * 256 * sizeof(double), st);
  col_stats<<<256, 256, 0, st>>>(t, stats, NN, 256);
  bn_apply_relu<<<(NN * 256 + 255) / 256, b256, 0, st>>>(t, feat_out, stats, bng, bnb,
                                                         NN, 256, 1);
}

// ---------------------------------------------------------------------------
// kernel_launch
// ---------------------------------------------------------------------------
extern "C" void kernel_launch(void* const* d_in, const int* in_sizes, int n_in,
                              void* d_out, int out_size, void* d_ws, size_t ws_size,
                              hipStream_t stream)
{
  const int*   edge_index = (const int*)d_in[0];
  const float* x      = (const float*)d_in[1];
  const int*   edge_id = (const int*)d_in[2];
  const float* W1     = (const float*)d_in[3];
  const float* a_src1 = (const float*)d_in[4];
  const float* a_dst1 = (const float*)d_in[5];
  const float* b1     = (const float*)d_in[6];
  const float* bn1_g  = (const float*)d_in[7];
  const float* bn1_b  = (const float*)d_in[8];
  const float* W2     = (const float*)d_in[9];
  const float* a_src2 = (const float*)d_in[10];
  const float* a_dst2 = (const float*)d_in[11];
  const float* b2     = (const float*)d_in[12];
  const float* bn2_g  = (const float*)d_in[13];
  const float* bn2_b  = (const float*)d_in[14];
  const float* lw1    = (const float*)d_in[15];
  const float* lb1    = (const float*)d_in[16];
  const float* bn3_g  = (const float*)d_in[17];
  const float* bn3_b  = (const float*)d_in[18];
  const float* lw2    = (const float*)d_in[19];
  const float* lb2    = (const float*)d_in[20];
  const float* bn4_g  = (const float*)d_in[21];
  const float* bn4_b  = (const float*)d_in[22];
  const float* fw     = (const float*)d_in[23];
  const float* fb     = (const float*)d_in[24];
  float* out = (float*)d_out;

  // ---- workspace arena (explicit aliasing) ----
  char* w = (char*)d_ws;
  float*    h_buf  = (float*)(w + 0);                    // [NN,512] 102.4 MB
  float*    t_buf  = (float*)(w + 102400000);            // [NN,256] (aggregate out)
  float*    z1     = (float*)(w + 0);                    // [NP,128] (aliases h_buf/t_buf, dead by then)
  float*    z2     = (float*)(w + 134217728);            // [NP,128]
  float*    feat1  = (float*)(w + 268435456);            // [NN,256] 51.2 MB
  float*    feat2  = (float*)(w + 319635456);            // [NN,256] 51.2 MB
  // CSR region (reuses old alpha region)
  int*      csr_src = (int*)(w + 370835456);             // [ET] 3.4 MB
  int*      deg     = (int*)(w + 374235456);             // [NN]
  int*      rowptr  = (int*)(w + 374435456);             // [NN+1]
  int*      cursor  = (int*)(w + 374635464);             // [NN]
  double*   stats   = (double*)(w + 378435456);          // 2*256 doubles
  float*    s_n     = (float*)(w + 378439552);           // [NN,2]
  float*    d_n     = (float*)(w + 378839552);           // [NN,2]

  dim3 b256(256);

  // ---- CSR build (once; same graph for both layers) ----
  hipMemsetAsync(deg, 0, NN * sizeof(int), stream);
  deg_count<<<(ET + 255) / 256, b256, 0, stream>>>(edge_index, deg);
  scan_deg<<<1, 1024, 0, stream>>>(deg, rowptr, cursor);
  scatter_edges<<<(ET + 255) / 256, b256, 0, stream>>>(edge_index, cursor, csr_src);

  // ---- GAT layer 1: x[NN,572] -> feat1[NN,256] ----
  gat_layer(x, 572, W1, a_src1, a_dst1, b1, bn1_g, bn1_b, rowptr, csr_src,
            h_buf, t_buf, feat1, s_n, d_n, stats, stream);

  // ---- GAT layer 2: feat1 -> feat2 ----
  gat_layer(feat1, 256, W2, a_src2, a_dst2, b2, bn2_g, bn2_b, rowptr, csr_src,
            h_buf, t_buf, feat2, s_n, d_n, stats, stream);

  // ---- pair MLP ----
  gemm_f32<<<dim3(2, NP / 64), b256, 0, stream>>>(feat2, lw1, z1, NP, 128, 512,
                                                  lb1, edge_id, edge_id + NP);
  hipMemsetAsync(stats, 0, 2 * 128 * sizeof(double), stream);
  col_stats<<<512, 128, 0, stream>>>(z1, stats, NP, 128);
  bn_apply_relu<<<(NP * 128 + 255) / 256, b256, 0, stream>>>(z1, z1, stats, bn3_g, bn3_b,
                                                             NP, 128, 1);
  gemm_f32<<<dim3(2, NP / 64), b256, 0, stream>>>(z1, lw2, z2, NP, 128, 128,
                                                  lb2, nullptr, nullptr);
  hipMemsetAsync(stats, 0, 2 * 128 * sizeof(double), stream);
  col_stats<<<512, 128, 0, stream>>>(z2, stats, NP, 128);
  bn_apply_relu<<<(NP * 128 + 255) / 256, b256, 0, stream>>>(z2, z2, stats, bn4_g, bn4_b,
                                                             NP, 128, 1);
  gemm_f32<<<dim3(2, NP / 64), b256, 0, stream>>>(z2, fw, out, NP, 65, 128,
                                                  fb, nullptr, nullptr);
}

// Round 3
// 1786.430 us; speedup vs baseline: 8.2574x; 2.1024x over previous
//
#include <hip/hip_runtime.h>

// ---------------------------------------------------------------------------
// Problem constants
// ---------------------------------------------------------------------------
constexpr int NN = 50000;            // nodes
constexpr int NE = 800000;           // edges (before self loops)
constexpr int NP = 262144;           // pairs
constexpr int ET = NE + NN;          // edges incl self loops

using short8 = __attribute__((ext_vector_type(8))) short;
using f32x4  = __attribute__((ext_vector_type(4))) float;

__device__ __forceinline__ ushort f2b(float f) {   // fp32 -> bf16 RNE
  unsigned u = __float_as_uint(f);
  return (ushort)((u + 0x7FFFu + ((u >> 16) & 1u)) >> 16);
}
__device__ __forceinline__ float b2f(ushort b) {
  return __uint_as_float(((unsigned)b) << 16);
}

// ---------------------------------------------------------------------------
// bf16 MFMA GEMM: C[M,N] = A[M,Kpad] @ BT[Npad,Kpad]^T  (+bias)
// 128x128 block tile, BK=32, 4 waves of 64x64 (4x4 grid of 16x16x32 MFMA).
// A,BT bf16 (ushort); C fp32 or bf16. GATHER: A row r = concat(feat[idx0[r]],
// feat[idx1[r]]) with feat rows of 256 bf16 (Kpad must be 512).
// ---------------------------------------------------------------------------
template<bool GATHER, bool OUT_BF16>
__global__ __launch_bounds__(256)
void mfma_gemm(const ushort* __restrict__ A, const ushort* __restrict__ BT,
               void* __restrict__ Cp, int M, int N, int Kpad, int Cld,
               const float* __restrict__ bias,
               const int* __restrict__ idx0, const int* __restrict__ idx1)
{
  __shared__ ushort As[128 * 40];   // stride 40 (+8 pad): 2-way-max bank alias
  __shared__ ushort Bs[128 * 40];
  const int tid = threadIdx.x;
  const int lane = tid & 63;
  const int wave = tid >> 6;
  const int row0 = blockIdx.y * 128, col0 = blockIdx.x * 128;
  const int wm = (wave >> 1) * 64, wn = (wave & 1) * 64;
  const int lrow = lane & 15, lk = (lane >> 4) * 8;

  f32x4 acc[4][4];
  #pragma unroll
  for (int i = 0; i < 4; ++i)
    #pragma unroll
    for (int j = 0; j < 4; ++j)
      acc[i][j] = (f32x4){0.f, 0.f, 0.f, 0.f};

  for (int kt = 0; kt < Kpad; kt += 32) {
    // stage A tile [128 rows x 32 k], 16B chunks
    #pragma unroll
    for (int c = tid; c < 512; c += 256) {
      int m = c >> 2, c8 = c & 3;
      int r = row0 + m;
      int kk = kt + c8 * 8;
      uint4 v = {0u, 0u, 0u, 0u};
      if (r < M) {
        const ushort* sp;
        if (GATHER) {
          int node = (kk < 256) ? idx0[r] : idx1[r];
          sp = A + (size_t)node * 256 + (kk & 255);
        } else {
          sp = A + (size_t)r * Kpad + kk;
        }
        v = *(const uint4*)sp;
      }
      *(uint4*)(As + m * 40 + c8 * 8) = v;
    }
    // stage B tile [128 cols x 32 k] from pre-transposed BT
    #pragma unroll
    for (int c = tid; c < 512; c += 256) {
      int n = c >> 2, c8 = c & 3;
      *(uint4*)(Bs + n * 40 + c8 * 8) =
          *(const uint4*)(BT + (size_t)(col0 + n) * Kpad + kt + c8 * 8);
    }
    __syncthreads();

    short8 af[4], bfr[4];
    #pragma unroll
    for (int i = 0; i < 4; ++i)
      af[i] = *(const short8*)(As + (wm + i * 16 + lrow) * 40 + lk);
    #pragma unroll
    for (int j = 0; j < 4; ++j)
      bfr[j] = *(const short8*)(Bs + (wn + j * 16 + lrow) * 40 + lk);
    #pragma unroll
    for (int i = 0; i < 4; ++i)
      #pragma unroll
      for (int j = 0; j < 4; ++j)
        acc[i][j] = __builtin_amdgcn_mfma_f32_16x16x32_bf16(af[i], bfr[j],
                                                            acc[i][j], 0, 0, 0);
    __syncthreads();
  }

  // epilogue: D mapping col=lane&15, row=(lane>>4)*4+reg
  #pragma unroll
  for (int i = 0; i < 4; ++i) {
    int r0 = row0 + wm + i * 16 + (lane >> 4) * 4;
    #pragma unroll
    for (int j = 0; j < 4; ++j) {
      int col = col0 + wn + j * 16 + lrow;
      if (col >= N) continue;
      float bv = bias ? bias[col] : 0.f;
      #pragma unroll
      for (int rg = 0; rg < 4; ++rg) {
        int row = r0 + rg;
        if (row >= M) continue;
        float val = acc[i][j][rg] + bv;
        if (OUT_BF16)
          ((ushort*)Cp)[(size_t)row * Cld + col] = f2b(val);
        else
          ((float*)Cp)[(size_t)row * Cld + col] = val;
      }
    }
  }
}

// ---------------------------------------------------------------------------
// Weight prep: W[K][N] fp32 -> BT[Npad][Kpad] bf16 (zero padded)
// ---------------------------------------------------------------------------
__global__ void transpose_w(const float* __restrict__ W, ushort* __restrict__ BT,
                            int K, int N, int Kpad, int Npad)
{
  int i = blockIdx.x * blockDim.x + threadIdx.x;
  if (i >= Npad * Kpad) return;
  int n = i / Kpad, k = i % Kpad;
  float v = (n < N && k < K) ? W[(size_t)k * N + n] : 0.f;
  BT[i] = f2b(v);
}

// x[NN][572] fp32 -> xb[NN][576] bf16 (zero padded)
__global__ void conv_x(const float* __restrict__ x, ushort* __restrict__ xb)
{
  int i = blockIdx.x * blockDim.x + threadIdx.x;
  if (i >= NN * 576) return;
  int r = i / 576, c = i % 576;
  xb[i] = f2b(c < 572 ? x[(size_t)r * 572 + c] : 0.f);
}

// ---------------------------------------------------------------------------
// CSR build (graph identical for both layers -> build once per call)
// ---------------------------------------------------------------------------
__global__ void deg_count(const int* __restrict__ ei, int* __restrict__ deg)
{
  int e = blockIdx.x * blockDim.x + threadIdx.x;
  if (e >= ET) return;
  int dst = (e < NE) ? ei[NE + e] : e - NE;
  atomicAdd(&deg[dst], 1);
}

__global__ __launch_bounds__(1024)
void scan_deg(const int* __restrict__ deg, int* __restrict__ rowptr,
              int* __restrict__ cursor)
{
  __shared__ int tot[1024];
  const int t = threadIdx.x;
  const int CH = (NN + 1023) / 1024;
  const int base = t * CH;
  int s = 0;
  for (int i = 0; i < CH; ++i) {
    int idx = base + i;
    if (idx < NN) s += deg[idx];
  }
  tot[t] = s;
  __syncthreads();
  for (int off = 1; off < 1024; off <<= 1) {
    int v = (t >= off) ? tot[t - off] : 0;
    __syncthreads();
    tot[t] += v;
    __syncthreads();
  }
  int run = (t == 0) ? 0 : tot[t - 1];
  for (int i = 0; i < CH; ++i) {
    int idx = base + i;
    if (idx <= NN) { rowptr[idx] = run; if (idx < NN) cursor[idx] = run; }
    if (idx < NN) run += deg[idx];
  }
}

__global__ void scatter_edges(const int* __restrict__ ei, int* __restrict__ cursor,
                              int* __restrict__ csr_src)
{
  int e = blockIdx.x * blockDim.x + threadIdx.x;
  if (e >= ET) return;
  int src, dst;
  if (e < NE) { src = ei[e]; dst = ei[NE + e]; }
  else        { src = dst = e - NE; }
  int pos = atomicAdd(&cursor[dst], 1);
  csr_src[pos] = src;
}

// ---------------------------------------------------------------------------
// GAT helpers (h in bf16)
// ---------------------------------------------------------------------------
__global__ void node_coeffs(const ushort* __restrict__ hb,
                            const float* __restrict__ a_src,
                            const float* __restrict__ a_dst,
                            float* __restrict__ s_n, float* __restrict__ d_n)
{
  int wid = (blockIdx.x * blockDim.x + threadIdx.x) >> 6;
  int lane = threadIdx.x & 63;
  if (wid >= NN * 2) return;
  int node = wid >> 1, head = wid & 1;
  ushort4 hv = *(const ushort4*)(hb + (size_t)node * 512 + head * 256 + lane * 4);
  float4 av = *(const float4*)(a_src + head * 256 + lane * 4);
  float4 dv = *(const float4*)(a_dst + head * 256 + lane * 4);
  float h0 = b2f(hv.x), h1 = b2f(hv.y), h2 = b2f(hv.z), h3 = b2f(hv.w);
  float ss = h0 * av.x + h1 * av.y + h2 * av.z + h3 * av.w;
  float dd = h0 * dv.x + h1 * dv.y + h2 * dv.z + h3 * dv.w;
  #pragma unroll
  for (int off = 32; off > 0; off >>= 1) {
    ss += __shfl_xor(ss, off);
    dd += __shfl_xor(dd, off);
  }
  if (lane == 0) { s_n[wid] = ss; d_n[wid] = dd; }
}

// One wave per dst node: softmax over incident edges + weighted aggregation.
__global__ __launch_bounds__(256)
void gat_aggregate(const int* __restrict__ rowptr, const int* __restrict__ csr_src,
                   const ushort* __restrict__ hb,
                   const float* __restrict__ s_n, const float* __restrict__ d_n,
                   const float* __restrict__ bias, float* __restrict__ outp)
{
  int wid = (blockIdx.x * blockDim.x + threadIdx.x) >> 6;
  int lane = threadIdx.x & 63;
  if (wid >= NN) return;
  const int dst = wid;
  const int beg = rowptr[dst], end = rowptr[dst + 1];
  const float d0 = d_n[dst * 2 + 0], d1 = d_n[dst * 2 + 1];
  const float2* sn2 = (const float2*)s_n;

  float m0 = -1e30f, m1 = -1e30f;
  for (int i = beg + lane; i < end; i += 64) {
    float2 sv = sn2[csr_src[i]];
    float a0 = sv.x + d0; a0 = a0 > 0.f ? a0 : 0.2f * a0;
    float a1 = sv.y + d1; a1 = a1 > 0.f ? a1 : 0.2f * a1;
    m0 = fmaxf(m0, a0); m1 = fmaxf(m1, a1);
  }
  #pragma unroll
  for (int off = 32; off > 0; off >>= 1) {
    m0 = fmaxf(m0, __shfl_xor(m0, off));
    m1 = fmaxf(m1, __shfl_xor(m1, off));
  }

  float z0 = 0.f, z1 = 0.f;
  for (int i = beg + lane; i < end; i += 64) {
    float2 sv = sn2[csr_src[i]];
    float a0 = sv.x + d0; a0 = a0 > 0.f ? a0 : 0.2f * a0;
    float a1 = sv.y + d1; a1 = a1 > 0.f ? a1 : 0.2f * a1;
    z0 += __expf(a0 - m0);
    z1 += __expf(a1 - m1);
  }
  #pragma unroll
  for (int off = 32; off > 0; off >>= 1) {
    z0 += __shfl_xor(z0, off);
    z1 += __shfl_xor(z1, off);
  }
  const float rz0 = 1.f / (z0 + 1e-16f);
  const float rz1 = 1.f / (z1 + 1e-16f);

  float4 acc0 = {0.f, 0.f, 0.f, 0.f};
  float4 acc1 = {0.f, 0.f, 0.f, 0.f};
  for (int i = beg; i < end; ++i) {
    int s = csr_src[i];
    float2 sv = sn2[s];
    float a0 = sv.x + d0; a0 = a0 > 0.f ? a0 : 0.2f * a0;
    float a1 = sv.y + d1; a1 = a1 > 0.f ? a1 : 0.2f * a1;
    float w0 = __expf(a0 - m0) * rz0;
    float w1 = __expf(a1 - m1) * rz1;
    ushort4 u0 = *(const ushort4*)(hb + (size_t)s * 512 + lane * 4);
    ushort4 u1 = *(const ushort4*)(hb + (size_t)s * 512 + 256 + lane * 4);
    acc0.x = fmaf(b2f(u0.x), w0, acc0.x); acc0.y = fmaf(b2f(u0.y), w0, acc0.y);
    acc0.z = fmaf(b2f(u0.z), w0, acc0.z); acc0.w = fmaf(b2f(u0.w), w0, acc0.w);
    acc1.x = fmaf(b2f(u1.x), w1, acc1.x); acc1.y = fmaf(b2f(u1.y), w1, acc1.y);
    acc1.z = fmaf(b2f(u1.z), w1, acc1.z); acc1.w = fmaf(b2f(u1.w), w1, acc1.w);
  }

  const float4 bb = *(const float4*)(bias + lane * 4);
  float4 o;
  o.x = 0.5f * (acc0.x + acc1.x) + bb.x;
  o.y = 0.5f * (acc0.y + acc1.y) + bb.y;
  o.z = 0.5f * (acc0.z + acc1.z) + bb.z;
  o.w = 0.5f * (acc0.w + acc1.w) + bb.w;
  *(float4*)(outp + (size_t)dst * 256 + lane * 4) = o;
}

// ---------------------------------------------------------------------------
// BatchNorm: fp32 stats (fp64 accum), apply + ReLU -> bf16
// ---------------------------------------------------------------------------
__global__ void col_stats(const float* __restrict__ x, double* __restrict__ stats,
                          int rows, int cols)
{
  int c = threadIdx.x;           // blockDim.x == cols
  double s = 0.0, q = 0.0;
  for (int r = blockIdx.x; r < rows; r += gridDim.x) {
    float v = x[(size_t)r * cols + c];
    s += v;
    q += (double)v * (double)v;
  }
  unsafeAtomicAdd(&stats[c], s);
  unsafeAtomicAdd(&stats[cols + c], q);
}

__global__ void bn_apply_relu_b(const float* __restrict__ x, ushort* __restrict__ y,
                                const double* __restrict__ stats,
                                const float* __restrict__ g, const float* __restrict__ b,
                                int rows, int cols)
{
  int i = blockIdx.x * blockDim.x + threadIdx.x;
  if (i >= rows * cols) return;
  int c = i % cols;
  float mean = (float)(stats[c] / rows);
  float var = (float)(stats[cols + c] / rows) - mean * mean;
  float rs = rsqrtf(var + 1e-5f);
  float v = g[c] * (x[i] - mean) * rs + b[c];
  v = fmaxf(v, 0.f);
  y[i] = f2b(v);
}

// ---------------------------------------------------------------------------
// Host-side GAT layer
// ---------------------------------------------------------------------------
static void gat_layer(const ushort* ain, int Kpad, const ushort* WT,
                      const float* asrc, const float* adst, const float* bias,
                      const float* bng, const float* bnb,
                      const int* rowptr, const int* csr_src,
                      ushort* hb, float* t, ushort* featb,
                      float* s_n, float* d_n, double* stats, hipStream_t st)
{
  dim3 b256(256);
  mfma_gemm<false, true><<<dim3(4, 391), b256, 0, st>>>(
      ain, WT, hb, NN, 512, Kpad, 512, nullptr, nullptr, nullptr);
  node_coeffs<<<(NN * 2 * 64 + 255) / 256, b256, 0, st>>>(hb, asrc, adst, s_n, d_n);
  gat_aggregate<<<(NN * 64 + 255) / 256, b256, 0, st>>>(rowptr, csr_src, hb,
                                                        s_n, d_n, bias, t);
  hipMemsetAsync(stats, 0, 2 * 256 * sizeof(double), st);
  col_stats<<<256, 256, 0, st>>>(t, stats, NN, 256);
  bn_apply_relu_b<<<(NN * 256 + 255) / 256, b256, 0, st>>>(t, featb, stats, bng, bnb,
                                                           NN, 256);
}

// ---------------------------------------------------------------------------
// kernel_launch
// ---------------------------------------------------------------------------
extern "C" void kernel_launch(void* const* d_in, const int* in_sizes, int n_in,
                              void* d_out, int out_size, void* d_ws, size_t ws_size,
                              hipStream_t stream)
{
  const int*   edge_index = (const int*)d_in[0];
  const float* x      = (const float*)d_in[1];
  const int*   edge_id = (const int*)d_in[2];
  const float* W1     = (const float*)d_in[3];
  const float* a_src1 = (const float*)d_in[4];
  const float* a_dst1 = (const float*)d_in[5];
  const float* b1     = (const float*)d_in[6];
  const float* bn1_g  = (const float*)d_in[7];
  const float* bn1_b  = (const float*)d_in[8];
  const float* W2     = (const float*)d_in[9];
  const float* a_src2 = (const float*)d_in[10];
  const float* a_dst2 = (const float*)d_in[11];
  const float* b2     = (const float*)d_in[12];
  const float* bn2_g  = (const float*)d_in[13];
  const float* bn2_b  = (const float*)d_in[14];
  const float* lw1    = (const float*)d_in[15];
  const float* lb1    = (const float*)d_in[16];
  const float* bn3_g  = (const float*)d_in[17];
  const float* bn3_b  = (const float*)d_in[18];
  const float* lw2    = (const float*)d_in[19];
  const float* lb2    = (const float*)d_in[20];
  const float* bn4_g  = (const float*)d_in[21];
  const float* bn4_b  = (const float*)d_in[22];
  const float* fw     = (const float*)d_in[23];
  const float* fb     = (const float*)d_in[24];
  float* out = (float*)d_out;

  // ---- workspace arena (explicit aliasing; ~302 MB) ----
  // Layers phase: xb@0, hb@57.6M, t@108.8M, feat1b@160M, feat2b@185.6M
  // Pairs phase:  z1@0 (xb/hb/t dead), z1b@160M (feat1b/feat2b dead after P1),
  //               z2@0 (z1 dead), z2b@227.1M
  char* w = (char*)d_ws;
  ushort* xb     = (ushort*)(w + 0);
  ushort* hb     = (ushort*)(w + 57600000);
  float*  t_buf  = (float*)(w + 108800000);
  ushort* feat1b = (ushort*)(w + 160000000);
  ushort* feat2b = (ushort*)(w + 185600000);
  float*  z1     = (float*)(w + 0);
  ushort* z1b    = (ushort*)(w + 160000000);
  float*  z2     = (float*)(w + 0);
  ushort* z2b    = (ushort*)(w + 227108864);
  int*    csr_src = (int*)(w + 294217728);
  int*    deg     = (int*)(w + 297700000);
  int*    rowptr  = (int*)(w + 297900000);
  int*    cursor  = (int*)(w + 298100008);
  float*  s_n     = (float*)(w + 298300008);
  float*  d_n     = (float*)(w + 298700008);
  double* stats   = (double*)(w + 299100008);
  ushort* W1T     = (ushort*)(w + 300000000);  // [512][576]
  ushort* W2T     = (ushort*)(w + 300600000);  // [512][256]
  ushort* LW1T    = (ushort*)(w + 300900000);  // [128][512]
  ushort* LW2T    = (ushort*)(w + 301040000);  // [128][128]
  ushort* FWT     = (ushort*)(w + 301080000);  // [128][128]

  dim3 b256(256);

  // ---- weight prep + input convert ----
  transpose_w<<<(512 * 576 + 255) / 256, b256, 0, stream>>>(W1, W1T, 572, 512, 576, 512);
  transpose_w<<<(512 * 256 + 255) / 256, b256, 0, stream>>>(W2, W2T, 256, 512, 256, 512);
  transpose_w<<<(128 * 512 + 255) / 256, b256, 0, stream>>>(lw1, LW1T, 512, 128, 512, 128);
  transpose_w<<<(128 * 128 + 255) / 256, b256, 0, stream>>>(lw2, LW2T, 128, 128, 128, 128);
  transpose_w<<<(128 * 128 + 255) / 256, b256, 0, stream>>>(fw, FWT, 128, 65, 128, 128);
  conv_x<<<(NN * 576 + 255) / 256, b256, 0, stream>>>(x, xb);

  // ---- CSR build ----
  hipMemsetAsync(deg, 0, NN * sizeof(int), stream);
  deg_count<<<(ET + 255) / 256, b256, 0, stream>>>(edge_index, deg);
  scan_deg<<<1, 1024, 0, stream>>>(deg, rowptr, cursor);
  scatter_edges<<<(ET + 255) / 256, b256, 0, stream>>>(edge_index, cursor, csr_src);

  // ---- GAT layers ----
  gat_layer(xb, 576, W1T, a_src1, a_dst1, b1, bn1_g, bn1_b, rowptr, csr_src,
            hb, t_buf, feat1b, s_n, d_n, stats, stream);
  gat_layer(feat1b, 256, W2T, a_src2, a_dst2, b2, bn2_g, bn2_b, rowptr, csr_src,
            hb, t_buf, feat2b, s_n, d_n, stats, stream);

  // ---- pair MLP ----
  mfma_gemm<true, false><<<dim3(1, 2048), b256, 0, stream>>>(
      feat2b, LW1T, z1, NP, 128, 512, 128, lb1, edge_id, edge_id + NP);
  hipMemsetAsync(stats, 0, 2 * 128 * sizeof(double), stream);
  col_stats<<<512, 128, 0, stream>>>(z1, stats, NP, 128);
  bn_apply_relu_b<<<(NP * 128 + 255) / 256, b256, 0, stream>>>(z1, z1b, stats,
                                                               bn3_g, bn3_b, NP, 128);
  mfma_gemm<false, false><<<dim3(1, 2048), b256, 0, stream>>>(
      z1b, LW2T, z2, NP, 128, 128, 128, lb2, nullptr, nullptr);
  hipMemsetAsync(stats, 0, 2 * 128 * sizeof(double), stream);
  col_stats<<<512, 128, 0, stream>>>(z2, stats, NP, 128);
  bn_apply_relu_b<<<(NP * 128 + 255) / 256, b256, 0, stream>>>(z2, z2b, stats,
                                                               bn4_g, bn4_b, NP, 128);
  mfma_gemm<false, false><<<dim3(1, 2048), b256, 0, stream>>>(
      z2b, FWT, out, NP, 65, 128, 65, fb, nullptr, nullptr);
}

// Round 4
// 1488.471 us; speedup vs baseline: 9.9104x; 1.2002x over previous
//
#include <hip/hip_runtime.h>

// ---------------------------------------------------------------------------
// Problem constants
// ---------------------------------------------------------------------------
constexpr int NN = 50000;            // nodes
constexpr int NE = 800000;           // edges (before self loops)
constexpr int NP = 262144;           // pairs
constexpr int ET = NE + NN;          // edges incl self loops

using short8 = __attribute__((ext_vector_type(8))) short;
using f32x4  = __attribute__((ext_vector_type(4))) float;

__device__ __forceinline__ ushort f2b(float f) {   // fp32 -> bf16 RNE
  unsigned u = __float_as_uint(f);
  return (ushort)((u + 0x7FFFu + ((u >> 16) & 1u)) >> 16);
}
__device__ __forceinline__ float b2f(ushort b) {
  return __uint_as_float(((unsigned)b) << 16);
}

// ---------------------------------------------------------------------------
// bf16 MFMA GEMM: C[M,N] = A[M,Kpad] @ BT[Npad,Kpad]^T  (+bias)
// 128x128 block tile, BK=32, 4 waves of 64x64 (4x4 grid of 16x16x32 MFMA).
// GATHER: A row r = concat(feat[idx0[r]], feat[idx1[r]]), feat rows 256 bf16.
// STATS: per-column sum/sumsq of the (bias-added) output accumulated into
//        stats[0..N-1] (sum) / stats[N..2N-1] (sumsq) via LDS + fp64 atomics.
//        Requires N == 128 (single column block). Rows must tile M exactly
//        for exact stats (true for NP = 2048*128).
// ---------------------------------------------------------------------------
template<bool GATHER, bool OUT_BF16, bool STATS>
__global__ __launch_bounds__(256)
void mfma_gemm(const ushort* __restrict__ A, const ushort* __restrict__ BT,
               void* __restrict__ Cp, int M, int N, int Kpad, int Cld,
               const float* __restrict__ bias,
               const int* __restrict__ idx0, const int* __restrict__ idx1,
               double* __restrict__ stats)
{
  __shared__ __align__(16) ushort As[128 * 40];  // +8 pad: 2-way bank alias max
  __shared__ __align__(16) ushort Bs[128 * 40];
  const int tid = threadIdx.x;
  const int lane = tid & 63;
  const int wave = tid >> 6;
  const int row0 = blockIdx.y * 128, col0 = blockIdx.x * 128;
  const int wm = (wave >> 1) * 64, wn = (wave & 1) * 64;
  const int lrow = lane & 15, lk = (lane >> 4) * 8;

  f32x4 acc[4][4];
  #pragma unroll
  for (int i = 0; i < 4; ++i)
    #pragma unroll
    for (int j = 0; j < 4; ++j)
      acc[i][j] = (f32x4){0.f, 0.f, 0.f, 0.f};

  for (int kt = 0; kt < Kpad; kt += 32) {
    #pragma unroll
    for (int c = tid; c < 512; c += 256) {
      int m = c >> 2, c8 = c & 3;
      int r = row0 + m;
      int kk = kt + c8 * 8;
      uint4 v = {0u, 0u, 0u, 0u};
      if (r < M) {
        const ushort* sp;
        if (GATHER) {
          int node = (kk < 256) ? idx0[r] : idx1[r];
          sp = A + (size_t)node * 256 + (kk & 255);
        } else {
          sp = A + (size_t)r * Kpad + kk;
        }
        v = *(const uint4*)sp;
      }
      *(uint4*)(As + m * 40 + c8 * 8) = v;
    }
    #pragma unroll
    for (int c = tid; c < 512; c += 256) {
      int n = c >> 2, c8 = c & 3;
      *(uint4*)(Bs + n * 40 + c8 * 8) =
          *(const uint4*)(BT + (size_t)(col0 + n) * Kpad + kt + c8 * 8);
    }
    __syncthreads();

    short8 af[4], bfr[4];
    #pragma unroll
    for (int i = 0; i < 4; ++i)
      af[i] = *(const short8*)(As + (wm + i * 16 + lrow) * 40 + lk);
    #pragma unroll
    for (int j = 0; j < 4; ++j)
      bfr[j] = *(const short8*)(Bs + (wn + j * 16 + lrow) * 40 + lk);
    #pragma unroll
    for (int i = 0; i < 4; ++i)
      #pragma unroll
      for (int j = 0; j < 4; ++j)
        acc[i][j] = __builtin_amdgcn_mfma_f32_16x16x32_bf16(af[i], bfr[j],
                                                            acc[i][j], 0, 0, 0);
    __syncthreads();
  }

  // epilogue: D mapping col=lane&15, row=(lane>>4)*4+reg
  float* sacc = (float*)As;                 // reuse LDS: [128]{sum,sumsq}
  if constexpr (STATS) {
    sacc[tid] = 0.f;                        // 256 floats
    __syncthreads();
  }
  float cs[4] = {0.f, 0.f, 0.f, 0.f}, cq[4] = {0.f, 0.f, 0.f, 0.f};
  #pragma unroll
  for (int i = 0; i < 4; ++i) {
    int r0 = row0 + wm + i * 16 + (lane >> 4) * 4;
    #pragma unroll
    for (int j = 0; j < 4; ++j) {
      int col = col0 + wn + j * 16 + lrow;
      if (col >= N) continue;
      float bv = bias ? bias[col] : 0.f;
      #pragma unroll
      for (int rg = 0; rg < 4; ++rg) {
        int row = r0 + rg;
        if (row >= M) continue;
        float val = acc[i][j][rg] + bv;
        if (OUT_BF16)
          ((ushort*)Cp)[(size_t)row * Cld + col] = f2b(val);
        else
          ((float*)Cp)[(size_t)row * Cld + col] = val;
        if (STATS) { cs[j] += val; cq[j] += val * val; }
      }
    }
  }
  if constexpr (STATS) {
    #pragma unroll
    for (int j = 0; j < 4; ++j) {
      int cl = wn + j * 16 + lrow;          // local col (N==128, col0==0)
      atomicAdd(&sacc[2 * cl + 0], cs[j]);
      atomicAdd(&sacc[2 * cl + 1], cq[j]);
    }
    __syncthreads();
    if (tid < 128) {
      unsafeAtomicAdd(&stats[tid],       (double)sacc[2 * tid + 0]);
      unsafeAtomicAdd(&stats[128 + tid], (double)sacc[2 * tid + 1]);
    }
  }
}

// ---------------------------------------------------------------------------
// Weight prep: W[K][N] fp32 -> BT[Npad][Kpad] bf16 (zero padded)
// ---------------------------------------------------------------------------
__global__ void transpose_w(const float* __restrict__ W, ushort* __restrict__ BT,
                            int K, int N, int Kpad, int Npad)
{
  int i = blockIdx.x * blockDim.x + threadIdx.x;
  if (i >= Npad * Kpad) return;
  int n = i / Kpad, k = i % Kpad;
  float v = (n < N && k < K) ? W[(size_t)k * N + n] : 0.f;
  BT[i] = f2b(v);
}

// x[NN][572] fp32 -> xb[NN][576] bf16 (zero padded), 4 cols/thread
__global__ void conv_x(const float* __restrict__ x, ushort* __restrict__ xb)
{
  int i = blockIdx.x * blockDim.x + threadIdx.x;
  if (i >= NN * 144) return;
  int r = i / 144, c4 = (i % 144) * 4;
  ushort4 o = {0, 0, 0, 0};
  if (c4 < 572) {           // c4 <= 568 -> full float4 in-bounds
    float4 v = *(const float4*)(x + (size_t)r * 572 + c4);
    o.x = f2b(v.x); o.y = f2b(v.y); o.z = f2b(v.z); o.w = f2b(v.w);
  }
  *(ushort4*)(xb + (size_t)r * 576 + c4) = o;
}

// ---------------------------------------------------------------------------
// CSR build (graph identical for both layers -> build once per call)
// ---------------------------------------------------------------------------
__global__ void deg_count(const int* __restrict__ ei, int* __restrict__ deg)
{
  int e = blockIdx.x * blockDim.x + threadIdx.x;
  if (e >= ET) return;
  int dst = (e < NE) ? ei[NE + e] : e - NE;
  atomicAdd(&deg[dst], 1);
}

__global__ __launch_bounds__(1024)
void scan_deg(const int* __restrict__ deg, int* __restrict__ rowptr,
              int* __restrict__ cursor)
{
  __shared__ int tot[1024];
  const int t = threadIdx.x;
  const int CH = (NN + 1023) / 1024;
  const int base = t * CH;
  int s = 0;
  for (int i = 0; i < CH; ++i) {
    int idx = base + i;
    if (idx < NN) s += deg[idx];
  }
  tot[t] = s;
  __syncthreads();
  for (int off = 1; off < 1024; off <<= 1) {
    int v = (t >= off) ? tot[t - off] : 0;
    __syncthreads();
    tot[t] += v;
    __syncthreads();
  }
  int run = (t == 0) ? 0 : tot[t - 1];
  for (int i = 0; i < CH; ++i) {
    int idx = base + i;
    if (idx <= NN) { rowptr[idx] = run; if (idx < NN) cursor[idx] = run; }
    if (idx < NN) run += deg[idx];
  }
}

__global__ void scatter_edges(const int* __restrict__ ei, int* __restrict__ cursor,
                              int* __restrict__ csr_src)
{
  int e = blockIdx.x * blockDim.x + threadIdx.x;
  if (e >= ET) return;
  int src, dst;
  if (e < NE) { src = ei[e]; dst = ei[NE + e]; }
  else        { src = dst = e - NE; }
  int pos = atomicAdd(&cursor[dst], 1);
  csr_src[pos] = src;
}

// ---------------------------------------------------------------------------
// GAT helpers (h in bf16)
// ---------------------------------------------------------------------------

// one wave per node, both heads: lane loads 8 contiguous bf16 (16 B)
__global__ void node_coeffs(const ushort* __restrict__ hb,
                            const float* __restrict__ a_src,
                            const float* __restrict__ a_dst,
                            float* __restrict__ s_n, float* __restrict__ d_n)
{
  int node = (blockIdx.x * blockDim.x + threadIdx.x) >> 6;
  int lane = threadIdx.x & 63;
  if (node >= NN) return;
  int head = lane >> 5;                 // lanes 0-31 head0, 32-63 head1
  int cidx = (lane * 8) & 255;          // col within head
  short8 hv = *(const short8*)(hb + (size_t)node * 512 + lane * 8);
  float4 a0 = *(const float4*)(a_src + head * 256 + cidx);
  float4 a1 = *(const float4*)(a_src + head * 256 + cidx + 4);
  float4 d0 = *(const float4*)(a_dst + head * 256 + cidx);
  float4 d1 = *(const float4*)(a_dst + head * 256 + cidx + 4);
  float h0 = b2f((ushort)hv[0]), h1 = b2f((ushort)hv[1]);
  float h2 = b2f((ushort)hv[2]), h3 = b2f((ushort)hv[3]);
  float h4 = b2f((ushort)hv[4]), h5 = b2f((ushort)hv[5]);
  float h6 = b2f((ushort)hv[6]), h7 = b2f((ushort)hv[7]);
  float ss = h0*a0.x + h1*a0.y + h2*a0.z + h3*a0.w
           + h4*a1.x + h5*a1.y + h6*a1.z + h7*a1.w;
  float dd = h0*d0.x + h1*d0.y + h2*d0.z + h3*d0.w
           + h4*d1.x + h5*d1.y + h6*d1.z + h7*d1.w;
  #pragma unroll
  for (int off = 16; off > 0; off >>= 1) {   // reduce within 32-lane half
    ss += __shfl_xor(ss, off);
    dd += __shfl_xor(dd, off);
  }
  if ((lane & 31) == 0) {
    s_n[node * 2 + head] = ss;
    d_n[node * 2 + head] = dd;
  }
}

// One wave handles 8 dst nodes: edge softmax + aggregation + BN partial stats.
__global__ __launch_bounds__(256)
void gat_aggregate(const int* __restrict__ rowptr, const int* __restrict__ csr_src,
                   const ushort* __restrict__ hb,
                   const float* __restrict__ s_n, const float* __restrict__ d_n,
                   const float* __restrict__ bias, float* __restrict__ outp,
                   double* __restrict__ stats)
{
  __shared__ float sacc[512];               // [256] sum, [256] sumsq
  sacc[threadIdx.x] = 0.f;
  sacc[256 + threadIdx.x] = 0.f;
  __syncthreads();

  const int wave = threadIdx.x >> 6, lane = threadIdx.x & 63;
  const int base = blockIdx.x * 32 + wave * 8;
  const float4 bb = *(const float4*)(bias + lane * 4);
  const float2* sn2 = (const float2*)s_n;

  for (int n = 0; n < 8; ++n) {
    const int dst = base + n;
    if (dst < NN) {
      const int beg = rowptr[dst], end = rowptr[dst + 1];
      const float d0 = d_n[dst * 2 + 0], d1 = d_n[dst * 2 + 1];

      float m0 = -1e30f, m1 = -1e30f;
      for (int i = beg + lane; i < end; i += 64) {
        float2 sv = sn2[csr_src[i]];
        float a0 = sv.x + d0; a0 = a0 > 0.f ? a0 : 0.2f * a0;
        float a1 = sv.y + d1; a1 = a1 > 0.f ? a1 : 0.2f * a1;
        m0 = fmaxf(m0, a0); m1 = fmaxf(m1, a1);
      }
      #pragma unroll
      for (int off = 32; off > 0; off >>= 1) {
        m0 = fmaxf(m0, __shfl_xor(m0, off));
        m1 = fmaxf(m1, __shfl_xor(m1, off));
      }

      float z0 = 0.f, z1 = 0.f;
      for (int i = beg + lane; i < end; i += 64) {
        float2 sv = sn2[csr_src[i]];
        float a0 = sv.x + d0; a0 = a0 > 0.f ? a0 : 0.2f * a0;
        float a1 = sv.y + d1; a1 = a1 > 0.f ? a1 : 0.2f * a1;
        z0 += __expf(a0 - m0);
        z1 += __expf(a1 - m1);
      }
      #pragma unroll
      for (int off = 32; off > 0; off >>= 1) {
        z0 += __shfl_xor(z0, off);
        z1 += __shfl_xor(z1, off);
      }
      const float rz0 = 1.f / (z0 + 1e-16f);
      const float rz1 = 1.f / (z1 + 1e-16f);

      float4 acc0 = {0.f, 0.f, 0.f, 0.f};
      float4 acc1 = {0.f, 0.f, 0.f, 0.f};
      for (int i = beg; i < end; ++i) {
        int s = csr_src[i];
        float2 sv = sn2[s];
        float a0 = sv.x + d0; a0 = a0 > 0.f ? a0 : 0.2f * a0;
        float a1 = sv.y + d1; a1 = a1 > 0.f ? a1 : 0.2f * a1;
        float w0 = __expf(a0 - m0) * rz0;
        float w1 = __expf(a1 - m1) * rz1;
        ushort4 u0 = *(const ushort4*)(hb + (size_t)s * 512 + lane * 4);
        ushort4 u1 = *(const ushort4*)(hb + (size_t)s * 512 + 256 + lane * 4);
        acc0.x = fmaf(b2f(u0.x), w0, acc0.x); acc0.y = fmaf(b2f(u0.y), w0, acc0.y);
        acc0.z = fmaf(b2f(u0.z), w0, acc0.z); acc0.w = fmaf(b2f(u0.w), w0, acc0.w);
        acc1.x = fmaf(b2f(u1.x), w1, acc1.x); acc1.y = fmaf(b2f(u1.y), w1, acc1.y);
        acc1.z = fmaf(b2f(u1.z), w1, acc1.z); acc1.w = fmaf(b2f(u1.w), w1, acc1.w);
      }

      float4 o;
      o.x = 0.5f * (acc0.x + acc1.x) + bb.x;
      o.y = 0.5f * (acc0.y + acc1.y) + bb.y;
      o.z = 0.5f * (acc0.z + acc1.z) + bb.z;
      o.w = 0.5f * (acc0.w + acc1.w) + bb.w;
      *(float4*)(outp + (size_t)dst * 256 + lane * 4) = o;

      const int c = lane * 4;
      atomicAdd(&sacc[c + 0], o.x);       atomicAdd(&sacc[c + 1], o.y);
      atomicAdd(&sacc[c + 2], o.z);       atomicAdd(&sacc[c + 3], o.w);
      atomicAdd(&sacc[256 + c + 0], o.x * o.x);
      atomicAdd(&sacc[256 + c + 1], o.y * o.y);
      atomicAdd(&sacc[256 + c + 2], o.z * o.z);
      atomicAdd(&sacc[256 + c + 3], o.w * o.w);
    }
  }
  __syncthreads();
  const int c = threadIdx.x;
  unsafeAtomicAdd(&stats[c],       (double)sacc[c]);
  unsafeAtomicAdd(&stats[256 + c], (double)sacc[256 + c]);
}

// ---------------------------------------------------------------------------
// BatchNorm: per-column scale/shift from stats, then vectorized apply+ReLU
// ---------------------------------------------------------------------------
__global__ void bn_prep(const double* __restrict__ stats,
                        const float* __restrict__ g, const float* __restrict__ b,
                        float* __restrict__ scale, float* __restrict__ shift,
                        int rows, int cols)
{
  int c = blockIdx.x * blockDim.x + threadIdx.x;
  if (c >= cols) return;
  float mean = (float)(stats[c] / rows);
  float var = (float)(stats[cols + c] / rows) - mean * mean;
  float rs = rsqrtf(var + 1e-5f);
  float sc = g[c] * rs;
  scale[c] = sc;
  shift[c] = b[c] - mean * sc;
}

__global__ void bn_apply_relu_b4(const float* __restrict__ x, ushort* __restrict__ y,
                                 const float* __restrict__ scale,
                                 const float* __restrict__ shift,
                                 int total4, int cols)
{
  int i = blockIdx.x * blockDim.x + threadIdx.x;
  if (i >= total4) return;
  int base = i * 4;
  int c = base % cols;                  // cols % 4 == 0 -> same row, 4 cols
  float4 xv = *(const float4*)(x + base);
  float4 sv = *(const float4*)(scale + c);
  float4 tv = *(const float4*)(shift + c);
  ushort4 o;
  o.x = f2b(fmaxf(fmaf(xv.x, sv.x, tv.x), 0.f));
  o.y = f2b(fmaxf(fmaf(xv.y, sv.y, tv.y), 0.f));
  o.z = f2b(fmaxf(fmaf(xv.z, sv.z, tv.z), 0.f));
  o.w = f2b(fmaxf(fmaf(xv.w, sv.w, tv.w), 0.f));
  *(ushort4*)(y + base) = o;
}

// ---------------------------------------------------------------------------
// Host-side GAT layer
// ---------------------------------------------------------------------------
static void gat_layer(const ushort* ain, int Kpad, const ushort* WT,
                      const float* asrc, const float* adst, const float* bias,
                      const float* bng, const float* bnb,
                      const int* rowptr, const int* csr_src,
                      ushort* hb, float* t, ushort* featb,
                      float* s_n, float* d_n, double* stats,
                      float* scale, float* shift, hipStream_t st)
{
  dim3 b256(256);
  mfma_gemm<false, true, false><<<dim3(4, 391), b256, 0, st>>>(
      ain, WT, hb, NN, 512, Kpad, 512, nullptr, nullptr, nullptr, nullptr);
  node_coeffs<<<(NN + 3) / 4, b256, 0, st>>>(hb, asrc, adst, s_n, d_n);
  gat_aggregate<<<(NN + 31) / 32, b256, 0, st>>>(rowptr, csr_src, hb,
                                                 s_n, d_n, bias, t, stats);
  bn_prep<<<1, 256, 0, st>>>(stats, bng, bnb, scale, shift, NN, 256);
  bn_apply_relu_b4<<<(NN * 64 + 255) / 256, b256, 0, st>>>(t, featb, scale, shift,
                                                           NN * 64, 256);
}

// ---------------------------------------------------------------------------
// kernel_launch
// ---------------------------------------------------------------------------
extern "C" void kernel_launch(void* const* d_in, const int* in_sizes, int n_in,
                              void* d_out, int out_size, void* d_ws, size_t ws_size,
                              hipStream_t stream)
{
  const int*   edge_index = (const int*)d_in[0];
  const float* x      = (const float*)d_in[1];
  const int*   edge_id = (const int*)d_in[2];
  const float* W1     = (const float*)d_in[3];
  const float* a_src1 = (const float*)d_in[4];
  const float* a_dst1 = (const float*)d_in[5];
  const float* b1     = (const float*)d_in[6];
  const float* bn1_g  = (const float*)d_in[7];
  const float* bn1_b  = (const float*)d_in[8];
  const float* W2     = (const float*)d_in[9];
  const float* a_src2 = (const float*)d_in[10];
  const float* a_dst2 = (const float*)d_in[11];
  const float* b2     = (const float*)d_in[12];
  const float* bn2_g  = (const float*)d_in[13];
  const float* bn2_b  = (const float*)d_in[14];
  const float* lw1    = (const float*)d_in[15];
  const float* lb1    = (const float*)d_in[16];
  const float* bn3_g  = (const float*)d_in[17];
  const float* bn3_b  = (const float*)d_in[18];
  const float* lw2    = (const float*)d_in[19];
  const float* lb2    = (const float*)d_in[20];
  const float* bn4_g  = (const float*)d_in[21];
  const float* bn4_b  = (const float*)d_in[22];
  const float* fw     = (const float*)d_in[23];
  const float* fb     = (const float*)d_in[24];
  float* out = (float*)d_out;

  // ---- workspace arena (explicit aliasing) ----
  char* w = (char*)d_ws;
  ushort* xb     = (ushort*)(w + 0);
  ushort* hb     = (ushort*)(w + 57600000);
  float*  t_buf  = (float*)(w + 108800000);
  ushort* feat1b = (ushort*)(w + 160000000);
  ushort* feat2b = (ushort*)(w + 185600000);
  float*  z1     = (float*)(w + 0);               // aliases xb/hb/t (dead)
  ushort* z1b    = (ushort*)(w + 160000000);      // aliases feat1b (dead)
  float*  z2     = (float*)(w + 0);               // aliases z1 (dead)
  ushort* z2b    = (ushort*)(w + 227108864);
  int*    csr_src = (int*)(w + 294217728);
  int*    deg     = (int*)(w + 297700000);
  int*    rowptr  = (int*)(w + 297900000);
  int*    cursor  = (int*)(w + 298100008);
  float*  s_n     = (float*)(w + 298300008);
  float*  d_n     = (float*)(w + 298700008);
  double* stats   = (double*)(w + 299100008);     // 4 x 512 doubles
  float*  scaleb  = (float*)(w + 299200000);      // 4 x 256 floats
  float*  shiftb  = (float*)(w + 299220000);      // 4 x 256 floats
  ushort* W1T     = (ushort*)(w + 300000000);     // [512][576]
  ushort* W2T     = (ushort*)(w + 300600000);     // [512][256]
  ushort* LW1T    = (ushort*)(w + 300900000);     // [128][512]
  ushort* LW2T    = (ushort*)(w + 301040000);     // [128][128]
  ushort* FWT     = (ushort*)(w + 301080000);     // [128][128]

  double* st1 = stats,        *st2 = stats + 512;
  double* st3 = stats + 1024, *st4 = stats + 1536;
  float* sc1 = scaleb, *sc2 = scaleb + 256, *sc3 = scaleb + 512, *sc4 = scaleb + 768;
  float* sh1 = shiftb, *sh2 = shiftb + 256, *sh3 = shiftb + 512, *sh4 = shiftb + 768;

  dim3 b256(256);

  // ---- zero all stats once (each buffer written exactly once per call) ----
  hipMemsetAsync(stats, 0, 4 * 512 * sizeof(double), stream);

  // ---- weight prep + input convert ----
  transpose_w<<<(512 * 576 + 255) / 256, b256, 0, stream>>>(W1, W1T, 572, 512, 576, 512);
  transpose_w<<<(512 * 256 + 255) / 256, b256, 0, stream>>>(W2, W2T, 256, 512, 256, 512);
  transpose_w<<<(128 * 512 + 255) / 256, b256, 0, stream>>>(lw1, LW1T, 512, 128, 512, 128);
  transpose_w<<<(128 * 128 + 255) / 256, b256, 0, stream>>>(lw2, LW2T, 128, 128, 128, 128);
  transpose_w<<<(128 * 128 + 255) / 256, b256, 0, stream>>>(fw, FWT, 128, 65, 128, 128);
  conv_x<<<(NN * 144 + 255) / 256, b256, 0, stream>>>(x, xb);

  // ---- CSR build ----
  hipMemsetAsync(deg, 0, NN * sizeof(int), stream);
  deg_count<<<(ET + 255) / 256, b256, 0, stream>>>(edge_index, deg);
  scan_deg<<<1, 1024, 0, stream>>>(deg, rowptr, cursor);
  scatter_edges<<<(ET + 255) / 256, b256, 0, stream>>>(edge_index, cursor, csr_src);

  // ---- GAT layers ----
  gat_layer(xb, 576, W1T, a_src1, a_dst1, b1, bn1_g, bn1_b, rowptr, csr_src,
            hb, t_buf, feat1b, s_n, d_n, st1, sc1, sh1, stream);
  gat_layer(feat1b, 256, W2T, a_src2, a_dst2, b2, bn2_g, bn2_b, rowptr, csr_src,
            hb, t_buf, feat2b, s_n, d_n, st2, sc2, sh2, stream);

  // ---- pair MLP ----
  mfma_gemm<true, false, true><<<dim3(1, 2048), b256, 0, stream>>>(
      feat2b, LW1T, z1, NP, 128, 512, 128, lb1, edge_id, edge_id + NP, st3);
  bn_prep<<<1, 128, 0, stream>>>(st3, bn3_g, bn3_b, sc3, sh3, NP, 128);
  bn_apply_relu_b4<<<(NP * 32 + 255) / 256, b256, 0, stream>>>(z1, z1b, sc3, sh3,
                                                               NP * 32, 128);
  mfma_gemm<false, false, true><<<dim3(1, 2048), b256, 0, stream>>>(
      z1b, LW2T, z2, NP, 128, 128, 128, lb2, nullptr, nullptr, st4);
  bn_prep<<<1, 128, 0, stream>>>(st4, bn4_g, bn4_b, sc4, sh4, NP, 128);
  bn_apply_relu_b4<<<(NP * 32 + 255) / 256, b256, 0, stream>>>(z2, z2b, sc4, sh4,
                                                               NP * 32, 128);
  mfma_gemm<false, false, false><<<dim3(1, 2048), b256, 0, stream>>>(
      z2b, FWT, out, NP, 65, 128, 65, fb, nullptr, nullptr, nullptr);
}

// Round 5
// 1464.165 us; speedup vs baseline: 10.0749x; 1.0166x over previous
//
#include <hip/hip_runtime.h>

// ---------------------------------------------------------------------------
// Problem constants
// ---------------------------------------------------------------------------
constexpr int NN = 50000;            // nodes
constexpr int NE = 800000;           // edges (before self loops)
constexpr int NP = 262144;           // pairs
constexpr int ET = NE + NN;          // edges incl self loops

using short8 = __attribute__((ext_vector_type(8))) short;
using f32x4  = __attribute__((ext_vector_type(4))) float;

__device__ __forceinline__ ushort f2b(float f) {   // fp32 -> bf16 RNE
  unsigned u = __float_as_uint(f);
  return (ushort)((u + 0x7FFFu + ((u >> 16) & 1u)) >> 16);
}
__device__ __forceinline__ float b2f(ushort b) {
  return __uint_as_float(((unsigned)b) << 16);
}

// ---------------------------------------------------------------------------
// bf16 MFMA GEMM: C[M,N] = A[M,Kpad] @ BT[Npad,Kpad]^T  (+bias)
// 128x128 block tile, BK=32, 4 waves of 64x64 (4x4 grid of 16x16x32 MFMA).
// GATHER: A row r = concat(feat[idx0[r]], feat[idx1[r]]), feat rows 256 bf16;
//         indices staged in LDS once (were re-read 16x per row).
// STATS: per-column sum/sumsq of output -> stats (N==128 only).
// ---------------------------------------------------------------------------
template<bool GATHER, bool OUT_BF16, bool STATS>
__global__ __launch_bounds__(256)
void mfma_gemm(const ushort* __restrict__ A, const ushort* __restrict__ BT,
               void* __restrict__ Cp, int M, int N, int Kpad, int Cld,
               const float* __restrict__ bias,
               const int* __restrict__ idx0, const int* __restrict__ idx1,
               double* __restrict__ stats)
{
  __shared__ __align__(16) ushort As[128 * 40];  // +8 pad: 2-way bank alias max
  __shared__ __align__(16) ushort Bs[128 * 40];
  __shared__ int idxs[256];
  const int tid = threadIdx.x;
  const int lane = tid & 63;
  const int wave = tid >> 6;
  const int row0 = blockIdx.y * 128, col0 = blockIdx.x * 128;
  const int wm = (wave >> 1) * 64, wn = (wave & 1) * 64;
  const int lrow = lane & 15, lk = (lane >> 4) * 8;

  if constexpr (GATHER) {
    if (tid < 128) {
      int r = row0 + tid;
      idxs[tid]       = (r < M) ? idx0[r] : 0;
      idxs[128 + tid] = (r < M) ? idx1[r] : 0;
    }
    __syncthreads();
  }

  f32x4 acc[4][4];
  #pragma unroll
  for (int i = 0; i < 4; ++i)
    #pragma unroll
    for (int j = 0; j < 4; ++j)
      acc[i][j] = (f32x4){0.f, 0.f, 0.f, 0.f};

  for (int kt = 0; kt < Kpad; kt += 32) {
    #pragma unroll
    for (int c = tid; c < 512; c += 256) {
      int m = c >> 2, c8 = c & 3;
      int r = row0 + m;
      int kk = kt + c8 * 8;
      uint4 v = {0u, 0u, 0u, 0u};
      if (r < M) {
        const ushort* sp;
        if (GATHER) {
          int node = (kk < 256) ? idxs[m] : idxs[128 + m];
          sp = A + (size_t)node * 256 + (kk & 255);
        } else {
          sp = A + (size_t)r * Kpad + kk;
        }
        v = *(const uint4*)sp;
      }
      *(uint4*)(As + m * 40 + c8 * 8) = v;
    }
    #pragma unroll
    for (int c = tid; c < 512; c += 256) {
      int n = c >> 2, c8 = c & 3;
      *(uint4*)(Bs + n * 40 + c8 * 8) =
          *(const uint4*)(BT + (size_t)(col0 + n) * Kpad + kt + c8 * 8);
    }
    __syncthreads();

    short8 af[4], bfr[4];
    #pragma unroll
    for (int i = 0; i < 4; ++i)
      af[i] = *(const short8*)(As + (wm + i * 16 + lrow) * 40 + lk);
    #pragma unroll
    for (int j = 0; j < 4; ++j)
      bfr[j] = *(const short8*)(Bs + (wn + j * 16 + lrow) * 40 + lk);
    #pragma unroll
    for (int i = 0; i < 4; ++i)
      #pragma unroll
      for (int j = 0; j < 4; ++j)
        acc[i][j] = __builtin_amdgcn_mfma_f32_16x16x32_bf16(af[i], bfr[j],
                                                            acc[i][j], 0, 0, 0);
    __syncthreads();
  }

  // epilogue: D mapping col=lane&15, row=(lane>>4)*4+reg
  float* sacc = (float*)As;                 // reuse LDS: [128]{sum,sumsq}
  if constexpr (STATS) {
    sacc[tid] = 0.f;
    __syncthreads();
  }
  float cs[4] = {0.f, 0.f, 0.f, 0.f}, cq[4] = {0.f, 0.f, 0.f, 0.f};
  #pragma unroll
  for (int i = 0; i < 4; ++i) {
    int r0 = row0 + wm + i * 16 + (lane >> 4) * 4;
    #pragma unroll
    for (int j = 0; j < 4; ++j) {
      int col = col0 + wn + j * 16 + lrow;
      if (col >= N) continue;
      float bv = bias ? bias[col] : 0.f;
      #pragma unroll
      for (int rg = 0; rg < 4; ++rg) {
        int row = r0 + rg;
        if (row >= M) continue;
        float val = acc[i][j][rg] + bv;
        if (OUT_BF16)
          ((ushort*)Cp)[(size_t)row * Cld + col] = f2b(val);
        else
          ((float*)Cp)[(size_t)row * Cld + col] = val;
        if (STATS) { cs[j] += val; cq[j] += val * val; }
      }
    }
  }
  if constexpr (STATS) {
    #pragma unroll
    for (int j = 0; j < 4; ++j) {
      int cl = wn + j * 16 + lrow;          // local col (N==128, col0==0)
      atomicAdd(&sacc[2 * cl + 0], cs[j]);
      atomicAdd(&sacc[2 * cl + 1], cq[j]);
    }
    __syncthreads();
    if (tid < 128) {
      unsafeAtomicAdd(&stats[tid],       (double)sacc[2 * tid + 0]);
      unsafeAtomicAdd(&stats[128 + tid], (double)sacc[2 * tid + 1]);
    }
  }
}

// ---------------------------------------------------------------------------
// Weight prep: all 5 transposes in one kernel. W[K][N] -> BT[Npad][Kpad] bf16.
//   seg0 W1T  [512][576] <- W1  (572x512)   294912
//   seg1 W2T  [512][256] <- W2  (256x512)   131072
//   seg2 LW1T [128][512] <- lw1 (512x128)    65536
//   seg3 LW2T [128][128] <- lw2 (128x128)    16384
//   seg4 FWT  [128][128] <- fw  (128x65)     16384   total = 524288
// ---------------------------------------------------------------------------
__global__ void prep_weights(const float* __restrict__ W1, ushort* __restrict__ W1T,
                             const float* __restrict__ W2, ushort* __restrict__ W2T,
                             const float* __restrict__ lw1, ushort* __restrict__ LW1T,
                             const float* __restrict__ lw2, ushort* __restrict__ LW2T,
                             const float* __restrict__ fw, ushort* __restrict__ FWT)
{
  int i = blockIdx.x * blockDim.x + threadIdx.x;
  const float* W; ushort* BT; int K, N, Kpad;
  if (i < 294912)      { W = W1;  BT = W1T;  K = 572; N = 512; Kpad = 576; }
  else if (i < 425984) { i -= 294912; W = W2;  BT = W2T;  K = 256; N = 512; Kpad = 256; }
  else if (i < 491520) { i -= 425984; W = lw1; BT = LW1T; K = 512; N = 128; Kpad = 512; }
  else if (i < 507904) { i -= 491520; W = lw2; BT = LW2T; K = 128; N = 128; Kpad = 128; }
  else                 { i -= 507904; W = fw;  BT = FWT;  K = 128; N = 65;  Kpad = 128; }
  int n = i / Kpad, k = i % Kpad;
  float v = (n < N && k < K) ? W[(size_t)k * N + n] : 0.f;
  BT[i] = f2b(v);
}

// x[NN][572] fp32 -> xb[NN][576] bf16 (zero padded), 4 cols/thread
__global__ void conv_x(const float* __restrict__ x, ushort* __restrict__ xb)
{
  int i = blockIdx.x * blockDim.x + threadIdx.x;
  if (i >= NN * 144) return;
  int r = i / 144, c4 = (i % 144) * 4;
  ushort4 o = {0, 0, 0, 0};
  if (c4 < 572) {           // c4 <= 568 -> full float4 in-bounds
    float4 v = *(const float4*)(x + (size_t)r * 572 + c4);
    o.x = f2b(v.x); o.y = f2b(v.y); o.z = f2b(v.z); o.w = f2b(v.w);
  }
  *(ushort4*)(xb + (size_t)r * 576 + c4) = o;
}

// ---------------------------------------------------------------------------
// CSR build (graph identical for both layers -> build once per call)
// ---------------------------------------------------------------------------
__global__ void deg_count(const int* __restrict__ ei, int* __restrict__ deg)
{
  int e = blockIdx.x * blockDim.x + threadIdx.x;
  if (e >= ET) return;
  int dst = (e < NE) ? ei[NE + e] : e - NE;
  atomicAdd(&deg[dst], 1);
}

__global__ __launch_bounds__(1024)
void scan_deg(const int* __restrict__ deg, int* __restrict__ rowptr,
              int* __restrict__ cursor)
{
  __shared__ int tot[1024];
  const int t = threadIdx.x;
  const int CH = (NN + 1023) / 1024;
  const int base = t * CH;
  int s = 0;
  for (int i = 0; i < CH; ++i) {
    int idx = base + i;
    if (idx < NN) s += deg[idx];
  }
  tot[t] = s;
  __syncthreads();
  for (int off = 1; off < 1024; off <<= 1) {
    int v = (t >= off) ? tot[t - off] : 0;
    __syncthreads();
    tot[t] += v;
    __syncthreads();
  }
  int run = (t == 0) ? 0 : tot[t - 1];
  for (int i = 0; i < CH; ++i) {
    int idx = base + i;
    if (idx <= NN) { rowptr[idx] = run; if (idx < NN) cursor[idx] = run; }
    if (idx < NN) run += deg[idx];
  }
}

__global__ void scatter_edges(const int* __restrict__ ei, int* __restrict__ cursor,
                              int* __restrict__ csr_src)
{
  int e = blockIdx.x * blockDim.x + threadIdx.x;
  if (e >= ET) return;
  int src, dst;
  if (e < NE) { src = ei[e]; dst = ei[NE + e]; }
  else        { src = dst = e - NE; }
  int pos = atomicAdd(&cursor[dst], 1);
  csr_src[pos] = src;
}

// ---------------------------------------------------------------------------
// GAT helpers (h in bf16)
// ---------------------------------------------------------------------------

// one wave per node, both heads: lane loads 8 contiguous bf16 (16 B)
__global__ void node_coeffs(const ushort* __restrict__ hb,
                            const float* __restrict__ a_src,
                            const float* __restrict__ a_dst,
                            float* __restrict__ s_n, float* __restrict__ d_n)
{
  int node = (blockIdx.x * blockDim.x + threadIdx.x) >> 6;
  int lane = threadIdx.x & 63;
  if (node >= NN) return;
  int head = lane >> 5;                 // lanes 0-31 head0, 32-63 head1
  int cidx = (lane * 8) & 255;          // col within head
  short8 hv = *(const short8*)(hb + (size_t)node * 512 + lane * 8);
  float4 a0 = *(const float4*)(a_src + head * 256 + cidx);
  float4 a1 = *(const float4*)(a_src + head * 256 + cidx + 4);
  float4 d0 = *(const float4*)(a_dst + head * 256 + cidx);
  float4 d1 = *(const float4*)(a_dst + head * 256 + cidx + 4);
  float h0 = b2f((ushort)hv[0]), h1 = b2f((ushort)hv[1]);
  float h2 = b2f((ushort)hv[2]), h3 = b2f((ushort)hv[3]);
  float h4 = b2f((ushort)hv[4]), h5 = b2f((ushort)hv[5]);
  float h6 = b2f((ushort)hv[6]), h7 = b2f((ushort)hv[7]);
  float ss = h0*a0.x + h1*a0.y + h2*a0.z + h3*a0.w
           + h4*a1.x + h5*a1.y + h6*a1.z + h7*a1.w;
  float dd = h0*d0.x + h1*d0.y + h2*d0.z + h3*d0.w
           + h4*d1.x + h5*d1.y + h6*d1.z + h7*d1.w;
  #pragma unroll
  for (int off = 16; off > 0; off >>= 1) {   // reduce within 32-lane half
    ss += __shfl_xor(ss, off);
    dd += __shfl_xor(dd, off);
  }
  if ((lane & 31) == 0) {
    s_n[node * 2 + head] = ss;
    d_n[node * 2 + head] = dd;
  }
}

// One wave handles 4 dst nodes: edge softmax + aggregation + BN partial stats.
__global__ __launch_bounds__(256)
void gat_aggregate(const int* __restrict__ rowptr, const int* __restrict__ csr_src,
                   const ushort* __restrict__ hb,
                   const float* __restrict__ s_n, const float* __restrict__ d_n,
                   const float* __restrict__ bias, float* __restrict__ outp,
                   double* __restrict__ stats)
{
  __shared__ float sacc[512];               // [256] sum, [256] sumsq
  sacc[threadIdx.x] = 0.f;
  sacc[256 + threadIdx.x] = 0.f;
  __syncthreads();

  const int wave = threadIdx.x >> 6, lane = threadIdx.x & 63;
  const int base = blockIdx.x * 16 + wave * 4;
  const float4 bb = *(const float4*)(bias + lane * 4);
  const float2* sn2 = (const float2*)s_n;

  for (int n = 0; n < 4; ++n) {
    const int dst = base + n;
    if (dst < NN) {
      const int beg = rowptr[dst], end = rowptr[dst + 1];
      const float d0 = d_n[dst * 2 + 0], d1 = d_n[dst * 2 + 1];

      float m0 = -1e30f, m1 = -1e30f;
      for (int i = beg + lane; i < end; i += 64) {
        float2 sv = sn2[csr_src[i]];
        float a0 = sv.x + d0; a0 = a0 > 0.f ? a0 : 0.2f * a0;
        float a1 = sv.y + d1; a1 = a1 > 0.f ? a1 : 0.2f * a1;
        m0 = fmaxf(m0, a0); m1 = fmaxf(m1, a1);
      }
      #pragma unroll
      for (int off = 32; off > 0; off >>= 1) {
        m0 = fmaxf(m0, __shfl_xor(m0, off));
        m1 = fmaxf(m1, __shfl_xor(m1, off));
      }

      float z0 = 0.f, z1 = 0.f;
      for (int i = beg + lane; i < end; i += 64) {
        float2 sv = sn2[csr_src[i]];
        float a0 = sv.x + d0; a0 = a0 > 0.f ? a0 : 0.2f * a0;
        float a1 = sv.y + d1; a1 = a1 > 0.f ? a1 : 0.2f * a1;
        z0 += __expf(a0 - m0);
        z1 += __expf(a1 - m1);
      }
      #pragma unroll
      for (int off = 32; off > 0; off >>= 1) {
        z0 += __shfl_xor(z0, off);
        z1 += __shfl_xor(z1, off);
      }
      const float rz0 = 1.f / (z0 + 1e-16f);
      const float rz1 = 1.f / (z1 + 1e-16f);

      float4 acc0 = {0.f, 0.f, 0.f, 0.f};
      float4 acc1 = {0.f, 0.f, 0.f, 0.f};
      int i = beg;
      for (; i + 2 <= end; i += 2) {          // 2x unroll: 4 outstanding loads
        int sA = csr_src[i], sB = csr_src[i + 1];
        const ushort4 uA0 = *(const ushort4*)(hb + (size_t)sA * 512 + lane * 4);
        const ushort4 uA1 = *(const ushort4*)(hb + (size_t)sA * 512 + 256 + lane * 4);
        const ushort4 uB0 = *(const ushort4*)(hb + (size_t)sB * 512 + lane * 4);
        const ushort4 uB1 = *(const ushort4*)(hb + (size_t)sB * 512 + 256 + lane * 4);
        float2 svA = sn2[sA], svB = sn2[sB];
        float aA0 = svA.x + d0; aA0 = aA0 > 0.f ? aA0 : 0.2f * aA0;
        float aA1 = svA.y + d1; aA1 = aA1 > 0.f ? aA1 : 0.2f * aA1;
        float aB0 = svB.x + d0; aB0 = aB0 > 0.f ? aB0 : 0.2f * aB0;
        float aB1 = svB.y + d1; aB1 = aB1 > 0.f ? aB1 : 0.2f * aB1;
        float wA0 = __expf(aA0 - m0) * rz0, wA1 = __expf(aA1 - m1) * rz1;
        float wB0 = __expf(aB0 - m0) * rz0, wB1 = __expf(aB1 - m1) * rz1;
        acc0.x = fmaf(b2f(uA0.x), wA0, acc0.x); acc0.y = fmaf(b2f(uA0.y), wA0, acc0.y);
        acc0.z = fmaf(b2f(uA0.z), wA0, acc0.z); acc0.w = fmaf(b2f(uA0.w), wA0, acc0.w);
        acc1.x = fmaf(b2f(uA1.x), wA1, acc1.x); acc1.y = fmaf(b2f(uA1.y), wA1, acc1.y);
        acc1.z = fmaf(b2f(uA1.z), wA1, acc1.z); acc1.w = fmaf(b2f(uA1.w), wA1, acc1.w);
        acc0.x = fmaf(b2f(uB0.x), wB0, acc0.x); acc0.y = fmaf(b2f(uB0.y), wB0, acc0.y);
        acc0.z = fmaf(b2f(uB0.z), wB0, acc0.z); acc0.w = fmaf(b2f(uB0.w), wB0, acc0.w);
        acc1.x = fmaf(b2f(uB1.x), wB1, acc1.x); acc1.y = fmaf(b2f(uB1.y), wB1, acc1.y);
        acc1.z = fmaf(b2f(uB1.z), wB1, acc1.z); acc1.w = fmaf(b2f(uB1.w), wB1, acc1.w);
      }
      if (i < end) {
        int s = csr_src[i];
        float2 sv = sn2[s];
        float a0 = sv.x + d0; a0 = a0 > 0.f ? a0 : 0.2f * a0;
        float a1 = sv.y + d1; a1 = a1 > 0.f ? a1 : 0.2f * a1;
        float w0 = __expf(a0 - m0) * rz0;
        float w1 = __expf(a1 - m1) * rz1;
        ushort4 u0 = *(const ushort4*)(hb + (size_t)s * 512 + lane * 4);
        ushort4 u1 = *(const ushort4*)(hb + (size_t)s * 512 + 256 + lane * 4);
        acc0.x = fmaf(b2f(u0.x), w0, acc0.x); acc0.y = fmaf(b2f(u0.y), w0, acc0.y);
        acc0.z = fmaf(b2f(u0.z), w0, acc0.z); acc0.w = fmaf(b2f(u0.w), w0, acc0.w);
        acc1.x = fmaf(b2f(u1.x), w1, acc1.x); acc1.y = fmaf(b2f(u1.y), w1, acc1.y);
        acc1.z = fmaf(b2f(u1.z), w1, acc1.z); acc1.w = fmaf(b2f(u1.w), w1, acc1.w);
      }

      float4 o;
      o.x = 0.5f * (acc0.x + acc1.x) + bb.x;
      o.y = 0.5f * (acc0.y + acc1.y) + bb.y;
      o.z = 0.5f * (acc0.z + acc1.z) + bb.z;
      o.w = 0.5f * (acc0.w + acc1.w) + bb.w;
      *(float4*)(outp + (size_t)dst * 256 + lane * 4) = o;

      const int c = lane * 4;
      atomicAdd(&sacc[c + 0], o.x);       atomicAdd(&sacc[c + 1], o.y);
      atomicAdd(&sacc[c + 2], o.z);       atomicAdd(&sacc[c + 3], o.w);
      atomicAdd(&sacc[256 + c + 0], o.x * o.x);
      atomicAdd(&sacc[256 + c + 1], o.y * o.y);
      atomicAdd(&sacc[256 + c + 2], o.z * o.z);
      atomicAdd(&sacc[256 + c + 3], o.w * o.w);
    }
  }
  __syncthreads();
  const int c = threadIdx.x;
  unsafeAtomicAdd(&stats[c],       (double)sacc[c]);
  unsafeAtomicAdd(&stats[256 + c], (double)sacc[256 + c]);
}

// ---------------------------------------------------------------------------
// BatchNorm apply (+ReLU) -> bf16; scale/shift computed inline from stats
// ---------------------------------------------------------------------------
__global__ void bn_apply_relu_b4(const float* __restrict__ x, ushort* __restrict__ y,
                                 const double* __restrict__ stats,
                                 const float* __restrict__ g, const float* __restrict__ b,
                                 int total4, int cols, float inv_rows)
{
  int i = blockIdx.x * blockDim.x + threadIdx.x;
  if (i >= total4) return;
  int base = i * 4;
  int c = base % cols;                  // cols % 4 == 0 -> same row, 4 cols
  float4 xv = *(const float4*)(x + base);
  float4 gv = *(const float4*)(g + c);
  float4 bv = *(const float4*)(b + c);
  ushort4 o;
  #pragma unroll
  for (int k = 0; k < 4; ++k) {
    float mean = (float)(stats[c + k] * (double)inv_rows);
    float var = (float)(stats[cols + c + k] * (double)inv_rows) - mean * mean;
    float sc = ((const float*)&gv)[k] * rsqrtf(var + 1e-5f);
    float sh = ((const float*)&bv)[k] - mean * sc;
    float v = fmaxf(fmaf(((const float*)&xv)[k], sc, sh), 0.f);
    ((ushort*)&o)[k] = f2b(v);
  }
  *(ushort4*)(y + base) = o;
}

// ---------------------------------------------------------------------------
// Host-side GAT layer
// ---------------------------------------------------------------------------
static void gat_layer(const ushort* ain, int Kpad, const ushort* WT,
                      const float* asrc, const float* adst, const float* bias,
                      const float* bng, const float* bnb,
                      const int* rowptr, const int* csr_src,
                      ushort* hb, float* t, ushort* featb,
                      float* s_n, float* d_n, double* stats, hipStream_t st)
{
  dim3 b256(256);
  mfma_gemm<false, true, false><<<dim3(4, 391), b256, 0, st>>>(
      ain, WT, hb, NN, 512, Kpad, 512, nullptr, nullptr, nullptr, nullptr);
  node_coeffs<<<(NN + 3) / 4, b256, 0, st>>>(hb, asrc, adst, s_n, d_n);
  gat_aggregate<<<(NN + 15) / 16, b256, 0, st>>>(rowptr, csr_src, hb,
                                                 s_n, d_n, bias, t, stats);
  bn_apply_relu_b4<<<(NN * 64 + 255) / 256, b256, 0, st>>>(
      t, featb, stats, bng, bnb, NN * 64, 256, 1.0f / NN);
}

// ---------------------------------------------------------------------------
// kernel_launch
// ---------------------------------------------------------------------------
extern "C" void kernel_launch(void* const* d_in, const int* in_sizes, int n_in,
                              void* d_out, int out_size, void* d_ws, size_t ws_size,
                              hipStream_t stream)
{
  const int*   edge_index = (const int*)d_in[0];
  const float* x      = (const float*)d_in[1];
  const int*   edge_id = (const int*)d_in[2];
  const float* W1     = (const float*)d_in[3];
  const float* a_src1 = (const float*)d_in[4];
  const float* a_dst1 = (const float*)d_in[5];
  const float* b1     = (const float*)d_in[6];
  const float* bn1_g  = (const float*)d_in[7];
  const float* bn1_b  = (const float*)d_in[8];
  const float* W2     = (const float*)d_in[9];
  const float* a_src2 = (const float*)d_in[10];
  const float* a_dst2 = (const float*)d_in[11];
  const float* b2     = (const float*)d_in[12];
  const float* bn2_g  = (const float*)d_in[13];
  const float* bn2_b  = (const float*)d_in[14];
  const float* lw1    = (const float*)d_in[15];
  const float* lb1    = (const float*)d_in[16];
  const float* bn3_g  = (const float*)d_in[17];
  const float* bn3_b  = (const float*)d_in[18];
  const float* lw2    = (const float*)d_in[19];
  const float* lb2    = (const float*)d_in[20];
  const float* bn4_g  = (const float*)d_in[21];
  const float* bn4_b  = (const float*)d_in[22];
  const float* fw     = (const float*)d_in[23];
  const float* fb     = (const float*)d_in[24];
  float* out = (float*)d_out;

  // ---- workspace arena (explicit aliasing) ----
  char* w = (char*)d_ws;
  ushort* xb     = (ushort*)(w + 0);
  ushort* hb     = (ushort*)(w + 57600000);
  float*  t_buf  = (float*)(w + 108800000);
  ushort* feat1b = (ushort*)(w + 160000000);
  ushort* feat2b = (ushort*)(w + 185600000);
  float*  z1     = (float*)(w + 0);               // aliases xb/hb/t (dead)
  ushort* z1b    = (ushort*)(w + 160000000);      // aliases feat1b (dead)
  float*  z2     = (float*)(w + 0);               // aliases z1 (dead)
  ushort* z2b    = (ushort*)(w + 227108864);
  int*    csr_src = (int*)(w + 294217728);
  int*    deg     = (int*)(w + 297700000);
  int*    rowptr  = (int*)(w + 297900000);
  int*    cursor  = (int*)(w + 298100008);
  float*  s_n     = (float*)(w + 298300008);
  float*  d_n     = (float*)(w + 298700008);
  double* stats   = (double*)(w + 299100008);     // 4 x 512 doubles
  ushort* W1T     = (ushort*)(w + 300000000);     // [512][576]
  ushort* W2T     = (ushort*)(w + 300600000);     // [512][256]
  ushort* LW1T    = (ushort*)(w + 300900000);     // [128][512]
  ushort* LW2T    = (ushort*)(w + 301040000);     // [128][128]
  ushort* FWT     = (ushort*)(w + 301080000);     // [128][128]

  double* st1 = stats,        *st2 = stats + 512;
  double* st3 = stats + 1024, *st4 = stats + 1536;

  dim3 b256(256);

  // ---- zero all stats once (each buffer written exactly once per call) ----
  hipMemsetAsync(stats, 0, 4 * 512 * sizeof(double), stream);

  // ---- weight prep + input convert ----
  prep_weights<<<2048, b256, 0, stream>>>(W1, W1T, W2, W2T, lw1, LW1T,
                                          lw2, LW2T, fw, FWT);
  conv_x<<<(NN * 144 + 255) / 256, b256, 0, stream>>>(x, xb);

  // ---- CSR build ----
  hipMemsetAsync(deg, 0, NN * sizeof(int), stream);
  deg_count<<<(ET + 255) / 256, b256, 0, stream>>>(edge_index, deg);
  scan_deg<<<1, 1024, 0, stream>>>(deg, rowptr, cursor);
  scatter_edges<<<(ET + 255) / 256, b256, 0, stream>>>(edge_index, cursor, csr_src);

  // ---- GAT layers ----
  gat_layer(xb, 576, W1T, a_src1, a_dst1, b1, bn1_g, bn1_b, rowptr, csr_src,
            hb, t_buf, feat1b, s_n, d_n, st1, stream);
  gat_layer(feat1b, 256, W2T, a_src2, a_dst2, b2, bn2_g, bn2_b, rowptr, csr_src,
            hb, t_buf, feat2b, s_n, d_n, st2, stream);

  // ---- pair MLP ----
  mfma_gemm<true, false, true><<<dim3(1, 2048), b256, 0, stream>>>(
      feat2b, LW1T, z1, NP, 128, 512, 128, lb1, edge_id, edge_id + NP, st3);
  bn_apply_relu_b4<<<(NP * 32 + 255) / 256, b256, 0, stream>>>(
      z1, z1b, st3, bn3_g, bn3_b, NP * 32, 128, 1.0f / NP);
  mfma_gemm<false, false, true><<<dim3(1, 2048), b256, 0, stream>>>(
      z1b, LW2T, z2, NP, 128, 128, 128, lb2, nullptr, nullptr, st4);
  bn_apply_relu_b4<<<(NP * 32 + 255) / 256, b256, 0, stream>>>(
      z2, z2b, st4, bn4_g, bn4_b, NP * 32, 128, 1.0f / NP);
  mfma_gemm<false, false, false><<<dim3(1, 2048), b256, 0, stream>>>(
      z2b, FWT, out, NP, 65, 128, 65, fb, nullptr, nullptr, nullptr);
}